// Round 1
// baseline (3775.707 us; speedup 1.0000x reference)
//
#include <hip/hip_runtime.h>
#include <math.h>

// Problem constants (fixed by the reference).
#define N_NODES 50000
#define N_EDGES 640000   // divisible by 128 (5000 tiles) and 256
#define NLAYER  4

__device__ __forceinline__ float gelu_f(float x) {
    // jax.nn.gelu default approximate=True (tanh form)
    return 0.5f * x * (1.0f + tanhf(0.7978845608028654f * (x + 0.044715f * x * x * x)));
}

// ---------------- CSR build (counting sort by dst) ----------------
__global__ void k_zero32(unsigned* p, int n) {
    int i = blockIdx.x * 256 + threadIdx.x;
    if (i < n) p[i] = 0u;
}

__global__ void k_hist(const int* __restrict__ dst, int* __restrict__ deg) {
    int i = blockIdx.x * 256 + threadIdx.x;
    if (i < N_EDGES) atomicAdd(&deg[dst[i]], 1);
}

__global__ void k_scan1(const int* __restrict__ deg, int* __restrict__ rowptr, int* __restrict__ bsum) {
    __shared__ int sd[1024];
    int gi = blockIdx.x * 1024 + threadIdx.x;
    int v = (gi < N_NODES) ? deg[gi] : 0;
    sd[threadIdx.x] = v;
    __syncthreads();
    for (int off = 1; off < 1024; off <<= 1) {
        int t2 = (threadIdx.x >= (unsigned)off) ? sd[threadIdx.x - off] : 0;
        __syncthreads();
        sd[threadIdx.x] += t2;
        __syncthreads();
    }
    if (gi < N_NODES) rowptr[gi] = sd[threadIdx.x] - v;  // block-local exclusive
    if (threadIdx.x == 1023) bsum[blockIdx.x] = sd[1023];
}

__global__ void k_scan2(const int* __restrict__ bsum, int* __restrict__ boff, int nb) {
    if (threadIdx.x == 0 && blockIdx.x == 0) {
        int run = 0;
        for (int b = 0; b < nb; b++) { boff[b] = run; run += bsum[b]; }
    }
}

__global__ void k_scan3(int* __restrict__ rowptr, const int* __restrict__ boff) {
    int gi = blockIdx.x * 1024 + threadIdx.x;
    if (gi < N_NODES) rowptr[gi] += boff[blockIdx.x];
    if (gi == 0) rowptr[N_NODES] = N_EDGES;
}

__global__ void k_copy(const int* __restrict__ a, int* __restrict__ b) {
    int i = blockIdx.x * 256 + threadIdx.x;
    if (i < N_NODES) b[i] = a[i];
}

__global__ void k_scatter(const int* __restrict__ dst, int* __restrict__ cursor, int* __restrict__ eidx) {
    int i = blockIdx.x * 256 + threadIdx.x;
    if (i < N_EDGES) {
        int p = atomicAdd(&cursor[dst[i]], 1);
        eidx[p] = i;
    }
}

// ---------------- feature encoder: h0 = gelu(feat@W1+b1)@W2+b2 ----------------
__global__ __launch_bounds__(256) void k_fe(
    const float* __restrict__ feat, const float* __restrict__ W1, const float* __restrict__ b1,
    const float* __restrict__ W2, const float* __restrict__ b2,
    float* __restrict__ h, float* __restrict__ out)
{
    __shared__ float hid[4][64];
    int w = threadIdx.x >> 6, lane = threadIdx.x & 63;
    int n = blockIdx.x * 4 + w;  // N divisible by 4
    float a = b1[lane];
#pragma unroll 8
    for (int k = 0; k < 32; k++) a = fmaf(feat[n * 32 + k], W1[k * 64 + lane], a);
    hid[w][lane] = gelu_f(a);
    __syncthreads();
    float o = b2[lane];
#pragma unroll 8
    for (int k = 0; k < 64; k++) o = fmaf(hid[w][k], W2[k * 64 + lane], o);
    h[n * 64 + lane] = o;
    out[n * 704 + 32 + lane] = o;
    if (lane < 32) out[n * 704 + lane] = feat[n * 32 + lane];
}

// ---------------- s = h @ [W_ni | W_nj | W_node(+b)]  -> [N,384] ----------------
// blockIdx.y in {0,1,2} selects the 128-col chunk. 8 nodes per iteration,
// activation rows read via wave-uniform global float4 (scalarizes to s_load).
__global__ __launch_bounds__(128) void k_node3(
    const float* __restrict__ h, const float* __restrict__ Wni,
    const float* __restrict__ Wnj, const float* __restrict__ Wnode,
    const float* __restrict__ bnode, float* __restrict__ s)
{
    int j = threadIdx.x;
    int c = blockIdx.y;
    const float* W = (c == 0) ? Wni : (c == 1) ? Wnj : Wnode;
    float bias = (c == 2) ? bnode[j] : 0.0f;
    for (int chunk = blockIdx.x; chunk < N_NODES / 8; chunk += gridDim.x) {
        int n0 = chunk * 8;
        float acc[8];
#pragma unroll
        for (int r = 0; r < 8; r++) acc[r] = bias;
        for (int k = 0; k < 64; k += 4) {
            float w0 = W[(k + 0) * 128 + j];
            float w1 = W[(k + 1) * 128 + j];
            float w2 = W[(k + 2) * 128 + j];
            float w3 = W[(k + 3) * 128 + j];
#pragma unroll
            for (int r = 0; r < 8; r++) {
                const float4 hv = *(const float4*)(h + (n0 + r) * 64 + k);
                acc[r] = fmaf(hv.x, w0, fmaf(hv.y, w1, fmaf(hv.z, w2, fmaf(hv.w, w3, acc[r]))));
            }
        }
#pragma unroll
        for (int r = 0; r < 8; r++) s[(size_t)(n0 + r) * 384 + c * 128 + j] = acc[r];
    }
}

// ---------------- fused edge kernel: ef(on the fly) @ W_fij + gathers -> e-vals ----------------
// Tile: 128 edges x 128 cols, K=64. 256 threads = 16tx x 16ty; micro-tile 8 edges x 8 cols.
// efT in LDS (k-major, stride 132), W_fij from global (32KB, L1-hot).
__global__ __launch_bounds__(256) void k_edge(
    const float* __restrict__ s, const float* __restrict__ Wfij,
    const float* __restrict__ attn,
    const float* __restrict__ type_emb, const float* __restrict__ rid_emb,
    const float* __restrict__ rcW, const float* __restrict__ rcb,
    const float* __restrict__ rpW, const float* __restrict__ rpb,
    const float* __restrict__ att_rc, const float* __restrict__ att_rp,
    const int* __restrict__ etype, const int* __restrict__ erid,
    const int* __restrict__ src, const int* __restrict__ dst,
    float* __restrict__ evals)
{
    __shared__ __align__(16) float efT[64 * 132];  // [k][edge], padded stride
    const int t = threadIdx.x;
    const int tx = t & 15, ty = t >> 4;
    const int j0 = tx * 8, m0 = ty * 8;
    float areg[8];
#pragma unroll
    for (int jj = 0; jj < 8; jj++) areg[jj] = attn[j0 + jj];
    const int e_local = t & 127;
    const int kgrp = (t >> 7) * 32;

    for (int tile = blockIdx.x; tile < N_EDGES / 128; tile += gridDim.x) {
        const int eb = tile * 128;
        __syncthreads();  // previous GEMM done before overwriting efT
        {   // Phase A: edge embedding into LDS (each thread: one edge, 32 k's)
            int e = eb + e_local;
            int et = etype[e] * 64, er = erid[e] * 64;
            float rc0 = att_rc[e * 2 + 0], rc1 = att_rc[e * 2 + 1];
            float rp0 = att_rp[e * 3 + 0], rp1 = att_rp[e * 3 + 1], rp2 = att_rp[e * 3 + 2];
            for (int kk = 0; kk < 32; kk++) {
                int k = kgrp + kk;
                float v = type_emb[et + k] + rid_emb[er + k] + rcb[k] + rpb[k];
                v = fmaf(rc0, rcW[k], v);
                v = fmaf(rc1, rcW[64 + k], v);
                v = fmaf(rp0, rpW[k], v);
                v = fmaf(rp1, rpW[64 + k], v);
                v = fmaf(rp2, rpW[128 + k], v);
                efT[k * 132 + e_local] = v;
            }
        }
        __syncthreads();
        // Phase B: register-tiled GEMM fij = efT^T @ W_fij
        float acc[8][8];
#pragma unroll
        for (int m = 0; m < 8; m++)
#pragma unroll
            for (int jj = 0; jj < 8; jj++) acc[m][jj] = 0.f;
        for (int k = 0; k < 64; k++) {
            const float4 a0 = *(const float4*)&efT[k * 132 + m0];
            const float4 a1 = *(const float4*)&efT[k * 132 + m0 + 4];
            const float4 b0 = *(const float4*)(Wfij + k * 128 + j0);
            const float4 b1 = *(const float4*)(Wfij + k * 128 + j0 + 4);
            float am[8] = {a0.x, a0.y, a0.z, a0.w, a1.x, a1.y, a1.z, a1.w};
            float bj[8] = {b0.x, b0.y, b0.z, b0.w, b1.x, b1.y, b1.z, b1.w};
#pragma unroll
            for (int m = 0; m < 8; m++)
#pragma unroll
                for (int jj = 0; jj < 8; jj++)
                    acc[m][jj] = fmaf(am[m], bj[jj], acc[m][jj]);
        }
        // Epilogue: + s_ni[src] + s_nj[dst], leaky_relu, dot attn, reduce over 8 tx
#pragma unroll
        for (int m = 0; m < 8; m++) {
            int e = eb + m0 + m;
            int es = src[e] * 384;
            int ed = dst[e] * 384 + 128;
            const float4 u0 = *(const float4*)(s + es + j0);
            const float4 u1 = *(const float4*)(s + es + j0 + 4);
            const float4 v0 = *(const float4*)(s + ed + j0);
            const float4 v1 = *(const float4*)(s + ed + j0 + 4);
            float uu[8] = {u0.x, u0.y, u0.z, u0.w, u1.x, u1.y, u1.z, u1.w};
            float vv[8] = {v0.x, v0.y, v0.z, v0.w, v1.x, v1.y, v1.z, v1.w};
            float p = 0.f;
#pragma unroll
            for (int jj = 0; jj < 8; jj++) {
                float f = acc[m][jj] + uu[jj] + vv[jj];
                f = (f >= 0.f) ? f : 0.2f * f;
                p = fmaf(f, areg[jj], p);
            }
            p += __shfl_xor(p, 1);
            p += __shfl_xor(p, 2);
            p += __shfl_xor(p, 4);
            if ((tx & 7) == 0) evals[e * 2 + (tx >> 3)] = p;  // head = tx>>3
        }
    }
}

// ---------------- per-dst softmax + aggregation (wave per node, CSR) ----------------
__global__ __launch_bounds__(256) void k_soft_agg(
    const int* __restrict__ rowptr, const int* __restrict__ eidx,
    const int* __restrict__ src, const float* __restrict__ evals,
    const float* __restrict__ s, float* __restrict__ agg)
{
    int lane = threadIdx.x & 63;
    int wid = (blockIdx.x * 256 + threadIdx.x) >> 6;
    int nw = (gridDim.x * 256) >> 6;
    for (int n = wid; n < N_NODES; n += nw) {
        int r0 = rowptr[n], r1 = rowptr[n + 1];
        if (r0 == r1) {
            agg[(size_t)n * 128 + lane] = 0.f;
            agg[(size_t)n * 128 + 64 + lane] = 0.f;
            continue;
        }
        float m0 = -1e30f, m1 = -1e30f;
        for (int i = r0 + lane; i < r1; i += 64) {
            int e = eidx[i];
            m0 = fmaxf(m0, evals[2 * e]);
            m1 = fmaxf(m1, evals[2 * e + 1]);
        }
#pragma unroll
        for (int off = 1; off < 64; off <<= 1) {
            m0 = fmaxf(m0, __shfl_xor(m0, off));
            m1 = fmaxf(m1, __shfl_xor(m1, off));
        }
        float z0 = 0.f, z1 = 0.f;
        for (int i = r0 + lane; i < r1; i += 64) {
            int e = eidx[i];
            z0 += expf(evals[2 * e] - m0);
            z1 += expf(evals[2 * e + 1] - m1);
        }
#pragma unroll
        for (int off = 1; off < 64; off <<= 1) {
            z0 += __shfl_xor(z0, off);
            z1 += __shfl_xor(z1, off);
        }
        float rz0 = 1.f / z0, rz1 = 1.f / z1;
        float a0 = 0.f, a1 = 0.f;
        for (int i = r0; i < r1; i++) {   // wave-uniform loop; lanes span feature dim
            int e = eidx[i];
            float w0 = expf(evals[2 * e] - m0) * rz0;
            float w1 = expf(evals[2 * e + 1] - m1) * rz1;
            int sb = src[e] * 384 + 256;  // h_out = s[:,256:384]
            a0 = fmaf(w0, s[sb + lane], a0);
            a1 = fmaf(w1, s[sb + 64 + lane], a1);
        }
        agg[(size_t)n * 128 + lane] = a0;
        agg[(size_t)n * 128 + 64 + lane] = a1;
    }
}

// ---------------- node MLP + residual: h' = gelu(agg@W1+b1)@W2+b2 + h ----------------
__global__ __launch_bounds__(128) void k_mlp(
    const float* __restrict__ agg, const float* __restrict__ W1, const float* __restrict__ b1,
    const float* __restrict__ W2, const float* __restrict__ b2,
    const float* __restrict__ hin, float* __restrict__ hout, float* __restrict__ out, int col0)
{
    __shared__ __align__(16) float hid[8 * 128];
    int j = threadIdx.x;
    for (int chunk = blockIdx.x; chunk < N_NODES / 8; chunk += gridDim.x) {
        int n0 = chunk * 8;
        float acc[8];
        float bb = b1[j];
#pragma unroll
        for (int r = 0; r < 8; r++) acc[r] = bb;
        for (int k = 0; k < 128; k += 4) {
            float w0 = W1[(k + 0) * 128 + j];
            float w1 = W1[(k + 1) * 128 + j];
            float w2 = W1[(k + 2) * 128 + j];
            float w3 = W1[(k + 3) * 128 + j];
#pragma unroll
            for (int r = 0; r < 8; r++) {
                const float4 av = *(const float4*)(agg + (size_t)(n0 + r) * 128 + k);
                acc[r] = fmaf(av.x, w0, fmaf(av.y, w1, fmaf(av.z, w2, fmaf(av.w, w3, acc[r]))));
            }
        }
#pragma unroll
        for (int r = 0; r < 8; r++) hid[r * 128 + j] = gelu_f(acc[r]);
        __syncthreads();
        if (j < 64) {
            float acc2[8];
            float bb2 = b2[j];
#pragma unroll
            for (int r = 0; r < 8; r++) acc2[r] = bb2;
            for (int k = 0; k < 128; k += 4) {
                float w0 = W2[(k + 0) * 64 + j];
                float w1 = W2[(k + 1) * 64 + j];
                float w2 = W2[(k + 2) * 64 + j];
                float w3 = W2[(k + 3) * 64 + j];
#pragma unroll
                for (int r = 0; r < 8; r++) {
                    const float4 hv = *(const float4*)&hid[r * 128 + k];
                    acc2[r] = fmaf(hv.x, w0, fmaf(hv.y, w1, fmaf(hv.z, w2, fmaf(hv.w, w3, acc2[r]))));
                }
            }
#pragma unroll
            for (int r = 0; r < 8; r++) {
                float v = acc2[r] + hin[(n0 + r) * 64 + j];
                hout[(n0 + r) * 64 + j] = v;
                out[(size_t)(n0 + r) * 704 + col0 + j] = v;
            }
        }
        __syncthreads();  // protect hid before next chunk
    }
}

// ---------------- graph max pooling over node_emb cols 0..351 ----------------
__device__ __forceinline__ unsigned fmap(float v) {
    unsigned u = __float_as_uint(v);
    return (u & 0x80000000u) ? ~u : (u | 0x80000000u);
}

__global__ __launch_bounds__(384) void k_colmax(const float* __restrict__ out, unsigned* __restrict__ gmax) {
    int c = threadIdx.x;
    if (c >= 352) return;
    float m = -1e30f;
    for (int n = blockIdx.x; n < N_NODES; n += gridDim.x)
        m = fmaxf(m, out[(size_t)n * 704 + c]);
    atomicMax(gmax + c, fmap(m));
}

__global__ __launch_bounds__(384) void k_bcast(const unsigned* __restrict__ gmax, float* __restrict__ out) {
    int c = threadIdx.x;
    if (c >= 352) return;
    unsigned u = gmax[c];
    u = (u & 0x80000000u) ? (u ^ 0x80000000u) : ~u;
    float v = __uint_as_float(u);
    for (int n = blockIdx.x; n < N_NODES; n += gridDim.x)
        out[(size_t)n * 704 + 352 + c] = v;
}

// ---------------- host launcher ----------------
extern "C" void kernel_launch(void* const* d_in, const int* in_sizes, int n_in,
                              void* d_out, int out_size, void* d_ws, size_t ws_size,
                              hipStream_t stream)
{
    (void)in_sizes; (void)n_in; (void)out_size; (void)ws_size;
    const float* feat     = (const float*)d_in[0];
    const float* att_rc   = (const float*)d_in[1];
    const float* att_rp   = (const float*)d_in[2];
    const float* type_emb = (const float*)d_in[3];
    const float* rid_emb  = (const float*)d_in[4];
    const float* rc_W     = (const float*)d_in[5];
    const float* rc_b     = (const float*)d_in[6];
    const float* rp_W     = (const float*)d_in[7];
    const float* rp_b     = (const float*)d_in[8];
    const float* fe_W1    = (const float*)d_in[9];
    const float* fe_b1    = (const float*)d_in[10];
    const float* fe_W2    = (const float*)d_in[11];
    const float* fe_b2    = (const float*)d_in[12];
    const float* W_ni     = (const float*)d_in[13];
    const float* W_nj     = (const float*)d_in[14];
    const float* W_fij    = (const float*)d_in[15];
    const float* W_node   = (const float*)d_in[16];
    const float* b_node   = (const float*)d_in[17];
    const float* attn     = (const float*)d_in[18];
    const float* mlp_W1   = (const float*)d_in[19];
    const float* mlp_b1   = (const float*)d_in[20];
    const float* mlp_W2   = (const float*)d_in[21];
    const float* mlp_b2   = (const float*)d_in[22];
    const int* src   = (const int*)d_in[23];
    const int* dst   = (const int*)d_in[24];
    const int* etype = (const int*)d_in[25];
    const int* erid  = (const int*)d_in[26];
    float* out = (float*)d_out;

    float* ws  = (float*)d_ws;
    float* h_a = ws;                                   // N*64
    float* h_b = h_a + (size_t)N_NODES * 64;           // N*64
    float* s   = h_b + (size_t)N_NODES * 64;           // N*384
    float* ev  = s + (size_t)N_NODES * 384;            // E*2
    float* agg = ev + (size_t)N_EDGES * 2;             // N*128
    int* deg    = (int*)(agg + (size_t)N_NODES * 128); // N
    int* rowptr = deg + N_NODES;                       // N+1
    int* cursor = rowptr + N_NODES + 1;                // N
    int* eidx   = cursor + N_NODES;                    // E
    int* bsum   = eidx + N_EDGES;                      // 64
    int* boff   = bsum + 64;                           // 64
    unsigned* gmax = (unsigned*)(boff + 64);           // 352

    const int NB = (N_NODES + 1023) / 1024;  // 49

    k_zero32<<<(N_NODES + 255) / 256, 256, 0, stream>>>((unsigned*)deg, N_NODES);
    k_zero32<<<2, 256, 0, stream>>>(gmax, 352);
    k_hist<<<N_EDGES / 256, 256, 0, stream>>>(dst, deg);
    k_scan1<<<NB, 1024, 0, stream>>>(deg, rowptr, bsum);
    k_scan2<<<1, 64, 0, stream>>>(bsum, boff, NB);
    k_scan3<<<NB, 1024, 0, stream>>>(rowptr, boff);
    k_copy<<<(N_NODES + 255) / 256, 256, 0, stream>>>(rowptr, cursor);
    k_scatter<<<N_EDGES / 256, 256, 0, stream>>>(dst, cursor, eidx);
    k_fe<<<N_NODES / 4, 256, 0, stream>>>(feat, fe_W1, fe_b1, fe_W2, fe_b2, h_a, out);

    float* hc = h_a;
    float* hn = h_b;
    for (int l = 0; l < NLAYER; l++) {
        k_node3<<<dim3(768, 3), 128, 0, stream>>>(hc, W_ni + l * 64 * 128, W_nj + l * 64 * 128,
                                                  W_node + l * 64 * 128, b_node + l * 128, s);
        k_edge<<<1280, 256, 0, stream>>>(s, W_fij + l * 64 * 128, attn + l * 128,
                                         type_emb, rid_emb, rc_W, rc_b, rp_W, rp_b,
                                         att_rc, att_rp, etype, erid, src, dst, ev);
        k_soft_agg<<<4096, 256, 0, stream>>>(rowptr, eidx, src, ev, s, agg);
        k_mlp<<<1024, 128, 0, stream>>>(agg, mlp_W1 + l * 128 * 128, mlp_b1 + l * 128,
                                        mlp_W2 + l * 128 * 64, mlp_b2 + l * 64,
                                        hc, hn, out, 32 + 64 * (l + 1));
        float* tmp = hc; hc = hn; hn = tmp;
    }
    k_colmax<<<512, 384, 0, stream>>>(out, gmax);
    k_bcast<<<512, 384, 0, stream>>>(gmax, out);
}

// Round 2
// 3770.400 us; speedup vs baseline: 1.0014x; 1.0014x over previous
//
#include <hip/hip_runtime.h>
#include <math.h>

// Problem constants (fixed by the reference).
#define N_NODES 50000
#define N_EDGES 640000   // divisible by 128 (5000 tiles) and 256
#define NLAYER  4

typedef unsigned short bf16_t;

__device__ __forceinline__ float gelu_f(float x) {
    // jax.nn.gelu default approximate=True (tanh form)
    return 0.5f * x * (1.0f + tanhf(0.7978845608028654f * (x + 0.044715f * x * x * x)));
}

__device__ __forceinline__ bf16_t f2bf(float f) {
    unsigned u = __float_as_uint(f);
    unsigned r = (u + 0x7FFFu + ((u >> 16) & 1u)) >> 16;   // RNE
    return (bf16_t)r;
}
__device__ __forceinline__ float bf2f(bf16_t h) { return __uint_as_float(((unsigned)h) << 16); }
__device__ __forceinline__ float bfl(unsigned x) { return __uint_as_float(x << 16); }
__device__ __forceinline__ float bfh(unsigned x) { return __uint_as_float(x & 0xFFFF0000u); }

// ---------------- CSR build (counting sort by dst) ----------------
__global__ void k_zero32(unsigned* p, int n) {
    int i = blockIdx.x * 256 + threadIdx.x;
    if (i < n) p[i] = 0u;
}

__global__ void k_hist(const int* __restrict__ dst, int* __restrict__ deg) {
    int i = blockIdx.x * 256 + threadIdx.x;
    if (i < N_EDGES) atomicAdd(&deg[dst[i]], 1);
}

__global__ void k_scan1(const int* __restrict__ deg, int* __restrict__ rowptr, int* __restrict__ bsum) {
    __shared__ int sd[1024];
    int gi = blockIdx.x * 1024 + threadIdx.x;
    int v = (gi < N_NODES) ? deg[gi] : 0;
    sd[threadIdx.x] = v;
    __syncthreads();
    for (int off = 1; off < 1024; off <<= 1) {
        int t2 = (threadIdx.x >= (unsigned)off) ? sd[threadIdx.x - off] : 0;
        __syncthreads();
        sd[threadIdx.x] += t2;
        __syncthreads();
    }
    if (gi < N_NODES) rowptr[gi] = sd[threadIdx.x] - v;  // block-local exclusive
    if (threadIdx.x == 1023) bsum[blockIdx.x] = sd[1023];
}

__global__ void k_scan2(const int* __restrict__ bsum, int* __restrict__ boff, int nb) {
    if (threadIdx.x == 0 && blockIdx.x == 0) {
        int run = 0;
        for (int b = 0; b < nb; b++) { boff[b] = run; run += bsum[b]; }
    }
}

__global__ void k_scan3(int* __restrict__ rowptr, const int* __restrict__ boff) {
    int gi = blockIdx.x * 1024 + threadIdx.x;
    if (gi < N_NODES) rowptr[gi] += boff[blockIdx.x];
    if (gi == 0) rowptr[N_NODES] = N_EDGES;
}

__global__ void k_copy(const int* __restrict__ a, int* __restrict__ b) {
    int i = blockIdx.x * 256 + threadIdx.x;
    if (i < N_NODES) b[i] = a[i];
}

__global__ void k_scatter(const int* __restrict__ dst, int* __restrict__ cursor, int* __restrict__ eidx) {
    int i = blockIdx.x * 256 + threadIdx.x;
    if (i < N_EDGES) {
        int p = atomicAdd(&cursor[dst[i]], 1);
        eidx[p] = i;
    }
}

// Gather all per-edge fields into dst-sorted order so downstream kernels are linear.
__global__ void k_sortgather(
    const int* __restrict__ eidx, const int* __restrict__ src, const int* __restrict__ dst,
    const int* __restrict__ etype, const int* __restrict__ erid,
    const float* __restrict__ att_rc, const float* __restrict__ att_rp,
    int* __restrict__ src_s, int* __restrict__ dst_s,
    int* __restrict__ etype_s, int* __restrict__ erid_s,
    float* __restrict__ rc_s, float* __restrict__ rp_s)
{
    int i = blockIdx.x * 256 + threadIdx.x;
    if (i < N_EDGES) {
        int e = eidx[i];
        src_s[i] = src[e];
        dst_s[i] = dst[e];
        etype_s[i] = etype[e];
        erid_s[i] = erid[e];
        rc_s[2 * i] = att_rc[2 * e];
        rc_s[2 * i + 1] = att_rc[2 * e + 1];
        rp_s[3 * i] = att_rp[3 * e];
        rp_s[3 * i + 1] = att_rp[3 * e + 1];
        rp_s[3 * i + 2] = att_rp[3 * e + 2];
    }
}

// ---------------- feature encoder: h0 = gelu(feat@W1+b1)@W2+b2 ----------------
__global__ __launch_bounds__(256) void k_fe(
    const float* __restrict__ feat, const float* __restrict__ W1, const float* __restrict__ b1,
    const float* __restrict__ W2, const float* __restrict__ b2,
    float* __restrict__ h, float* __restrict__ out)
{
    __shared__ float hid[4][64];
    int w = threadIdx.x >> 6, lane = threadIdx.x & 63;
    int n = blockIdx.x * 4 + w;  // N divisible by 4
    float a = b1[lane];
#pragma unroll 8
    for (int k = 0; k < 32; k++) a = fmaf(feat[n * 32 + k], W1[k * 64 + lane], a);
    hid[w][lane] = gelu_f(a);
    __syncthreads();
    float o = b2[lane];
#pragma unroll 8
    for (int k = 0; k < 64; k++) o = fmaf(hid[w][k], W2[k * 64 + lane], o);
    h[n * 64 + lane] = o;
    out[n * 704 + 32 + lane] = o;
    if (lane < 32) out[n * 704 + lane] = feat[n * 32 + lane];
}

// ---------------- s = h @ [W_ni | W_nj | W_node(+b)]  -> [N,384] bf16 ----------------
__global__ __launch_bounds__(128) void k_node3(
    const float* __restrict__ h, const float* __restrict__ Wni,
    const float* __restrict__ Wnj, const float* __restrict__ Wnode,
    const float* __restrict__ bnode, bf16_t* __restrict__ s)
{
    int j = threadIdx.x;
    int c = blockIdx.y;
    const float* W = (c == 0) ? Wni : (c == 1) ? Wnj : Wnode;
    float bias = (c == 2) ? bnode[j] : 0.0f;
    for (int chunk = blockIdx.x; chunk < N_NODES / 8; chunk += gridDim.x) {
        int n0 = chunk * 8;
        float acc[8];
#pragma unroll
        for (int r = 0; r < 8; r++) acc[r] = bias;
        for (int k = 0; k < 64; k += 4) {
            float w0 = W[(k + 0) * 128 + j];
            float w1 = W[(k + 1) * 128 + j];
            float w2 = W[(k + 2) * 128 + j];
            float w3 = W[(k + 3) * 128 + j];
#pragma unroll
            for (int r = 0; r < 8; r++) {
                const float4 hv = *(const float4*)(h + (n0 + r) * 64 + k);
                acc[r] = fmaf(hv.x, w0, fmaf(hv.y, w1, fmaf(hv.z, w2, fmaf(hv.w, w3, acc[r]))));
            }
        }
#pragma unroll
        for (int r = 0; r < 8; r++) s[(size_t)(n0 + r) * 384 + c * 128 + j] = f2bf(acc[r]);
    }
}

// ---------------- fused edge kernel (dst-sorted order) ----------------
// Tile: 128 edges x 128 cols, K=64. 256 threads = 16tx x 16ty; micro-tile 8x8.
__global__ __launch_bounds__(256, 3) void k_edge(
    const bf16_t* __restrict__ s, const float* __restrict__ Wfij,
    const float* __restrict__ attn,
    const float* __restrict__ type_emb, const float* __restrict__ rid_emb,
    const float* __restrict__ rcW, const float* __restrict__ rcb,
    const float* __restrict__ rpW, const float* __restrict__ rpb,
    const float* __restrict__ rc_s, const float* __restrict__ rp_s,
    const int* __restrict__ etype_s, const int* __restrict__ erid_s,
    const int* __restrict__ src_s, const int* __restrict__ dst_s,
    float* __restrict__ evals)
{
    __shared__ __align__(16) float efT[64 * 132];  // [k][edge], padded stride
    const int t = threadIdx.x;
    const int tx = t & 15, ty = t >> 4;
    const int j0 = tx * 8, m0 = ty * 8;
    float areg[8];
#pragma unroll
    for (int jj = 0; jj < 8; jj++) areg[jj] = attn[j0 + jj];
    const int e_local = t & 127;
    const int kgrp = (t >> 7) * 32;

    for (int tile = blockIdx.x; tile < N_EDGES / 128; tile += gridDim.x) {
        const int eb = tile * 128;
        __syncthreads();  // previous GEMM done before overwriting efT
        {   // Phase A: edge embedding into LDS (each thread: one edge, 32 k's)
            int i = eb + e_local;
            int et = etype_s[i] * 64, er = erid_s[i] * 64;
            float rc0 = rc_s[i * 2 + 0], rc1 = rc_s[i * 2 + 1];
            float rp0 = rp_s[i * 3 + 0], rp1 = rp_s[i * 3 + 1], rp2 = rp_s[i * 3 + 2];
            for (int kk = 0; kk < 32; kk++) {
                int k = kgrp + kk;
                float v = type_emb[et + k] + rid_emb[er + k] + rcb[k] + rpb[k];
                v = fmaf(rc0, rcW[k], v);
                v = fmaf(rc1, rcW[64 + k], v);
                v = fmaf(rp0, rpW[k], v);
                v = fmaf(rp1, rpW[64 + k], v);
                v = fmaf(rp2, rpW[128 + k], v);
                efT[k * 132 + e_local] = v;
            }
        }
        __syncthreads();
        // Phase B: register-tiled GEMM fij = efT^T @ W_fij
        float acc[8][8];
#pragma unroll
        for (int m = 0; m < 8; m++)
#pragma unroll
            for (int jj = 0; jj < 8; jj++) acc[m][jj] = 0.f;
        for (int k = 0; k < 64; k++) {
            const float4 a0 = *(const float4*)&efT[k * 132 + m0];
            const float4 a1 = *(const float4*)&efT[k * 132 + m0 + 4];
            const float4 b0 = *(const float4*)(Wfij + k * 128 + j0);
            const float4 b1 = *(const float4*)(Wfij + k * 128 + j0 + 4);
            float am[8] = {a0.x, a0.y, a0.z, a0.w, a1.x, a1.y, a1.z, a1.w};
            float bj[8] = {b0.x, b0.y, b0.z, b0.w, b1.x, b1.y, b1.z, b1.w};
#pragma unroll
            for (int m = 0; m < 8; m++)
#pragma unroll
                for (int jj = 0; jj < 8; jj++)
                    acc[m][jj] = fmaf(am[m], bj[jj], acc[m][jj]);
        }
        // Epilogue: + s_ni[src] + s_nj[dst] (bf16), leaky_relu, dot attn, reduce
#pragma unroll
        for (int m = 0; m < 8; m++) {
            int i = eb + m0 + m;
            size_t es = (size_t)src_s[i] * 384 + j0;
            size_t ed = (size_t)dst_s[i] * 384 + 128 + j0;
            const uint4 U = *(const uint4*)(s + es);
            const uint4 V = *(const uint4*)(s + ed);
            float uu[8] = {bfl(U.x), bfh(U.x), bfl(U.y), bfh(U.y), bfl(U.z), bfh(U.z), bfl(U.w), bfh(U.w)};
            float vv[8] = {bfl(V.x), bfh(V.x), bfl(V.y), bfh(V.y), bfl(V.z), bfh(V.z), bfl(V.w), bfh(V.w)};
            float p = 0.f;
#pragma unroll
            for (int jj = 0; jj < 8; jj++) {
                float f = acc[m][jj] + uu[jj] + vv[jj];
                f = (f >= 0.f) ? f : 0.2f * f;
                p = fmaf(f, areg[jj], p);
            }
            p += __shfl_xor(p, 1);
            p += __shfl_xor(p, 2);
            p += __shfl_xor(p, 4);
            if ((tx & 7) == 0) evals[i * 2 + (tx >> 3)] = p;  // head = tx>>3
        }
    }
}

// ---------------- per-dst softmax + aggregation (wave per node, sorted CSR) ----------------
__global__ __launch_bounds__(256) void k_soft_agg(
    const int* __restrict__ rowptr, const int* __restrict__ src_s,
    const float* __restrict__ evals, const bf16_t* __restrict__ s,
    float* __restrict__ agg)
{
    int lane = threadIdx.x & 63;
    int wid = (blockIdx.x * 256 + threadIdx.x) >> 6;
    int nw = (gridDim.x * 256) >> 6;
    for (int n = wid; n < N_NODES; n += nw) {
        int r0 = rowptr[n], r1 = rowptr[n + 1];
        if (r0 == r1) {
            agg[(size_t)n * 128 + lane] = 0.f;
            agg[(size_t)n * 128 + 64 + lane] = 0.f;
            continue;
        }
        float m0 = -1e30f, m1 = -1e30f;
        for (int i = r0 + lane; i < r1; i += 64) {
            m0 = fmaxf(m0, evals[2 * i]);
            m1 = fmaxf(m1, evals[2 * i + 1]);
        }
#pragma unroll
        for (int off = 1; off < 64; off <<= 1) {
            m0 = fmaxf(m0, __shfl_xor(m0, off));
            m1 = fmaxf(m1, __shfl_xor(m1, off));
        }
        float z0 = 0.f, z1 = 0.f;
        for (int i = r0 + lane; i < r1; i += 64) {
            z0 += expf(evals[2 * i] - m0);
            z1 += expf(evals[2 * i + 1] - m1);
        }
#pragma unroll
        for (int off = 1; off < 64; off <<= 1) {
            z0 += __shfl_xor(z0, off);
            z1 += __shfl_xor(z1, off);
        }
        float rz0 = 1.f / z0, rz1 = 1.f / z1;
        float a0 = 0.f, a1 = 0.f;
        for (int i = r0; i < r1; i++) {   // wave-uniform loop; lanes span feature dim
            float w0 = expf(evals[2 * i] - m0) * rz0;
            float w1 = expf(evals[2 * i + 1] - m1) * rz1;
            size_t sb = (size_t)src_s[i] * 384 + 256;  // h_out = s[:,256:384]
            a0 = fmaf(w0, bf2f(s[sb + lane]), a0);
            a1 = fmaf(w1, bf2f(s[sb + 64 + lane]), a1);
        }
        agg[(size_t)n * 128 + lane] = a0;
        agg[(size_t)n * 128 + 64 + lane] = a1;
    }
}

// ---------------- node MLP + residual: h' = gelu(agg@W1+b1)@W2+b2 + h ----------------
__global__ __launch_bounds__(128) void k_mlp(
    const float* __restrict__ agg, const float* __restrict__ W1, const float* __restrict__ b1,
    const float* __restrict__ W2, const float* __restrict__ b2,
    const float* __restrict__ hin, float* __restrict__ hout, float* __restrict__ out, int col0)
{
    __shared__ __align__(16) float hid[8 * 128];
    int j = threadIdx.x;
    for (int chunk = blockIdx.x; chunk < N_NODES / 8; chunk += gridDim.x) {
        int n0 = chunk * 8;
        float acc[8];
        float bb = b1[j];
#pragma unroll
        for (int r = 0; r < 8; r++) acc[r] = bb;
        for (int k = 0; k < 128; k += 4) {
            float w0 = W1[(k + 0) * 128 + j];
            float w1 = W1[(k + 1) * 128 + j];
            float w2 = W1[(k + 2) * 128 + j];
            float w3 = W1[(k + 3) * 128 + j];
#pragma unroll
            for (int r = 0; r < 8; r++) {
                const float4 av = *(const float4*)(agg + (size_t)(n0 + r) * 128 + k);
                acc[r] = fmaf(av.x, w0, fmaf(av.y, w1, fmaf(av.z, w2, fmaf(av.w, w3, acc[r]))));
            }
        }
#pragma unroll
        for (int r = 0; r < 8; r++) hid[r * 128 + j] = gelu_f(acc[r]);
        __syncthreads();
        if (j < 64) {
            float acc2[8];
            float bb2 = b2[j];
#pragma unroll
            for (int r = 0; r < 8; r++) acc2[r] = bb2;
            for (int k = 0; k < 128; k += 4) {
                float w0 = W2[(k + 0) * 64 + j];
                float w1 = W2[(k + 1) * 64 + j];
                float w2 = W2[(k + 2) * 64 + j];
                float w3 = W2[(k + 3) * 64 + j];
#pragma unroll
                for (int r = 0; r < 8; r++) {
                    const float4 hv = *(const float4*)&hid[r * 128 + k];
                    acc2[r] = fmaf(hv.x, w0, fmaf(hv.y, w1, fmaf(hv.z, w2, fmaf(hv.w, w3, acc2[r]))));
                }
            }
#pragma unroll
            for (int r = 0; r < 8; r++) {
                float v = acc2[r] + hin[(n0 + r) * 64 + j];
                hout[(n0 + r) * 64 + j] = v;
                out[(size_t)(n0 + r) * 704 + col0 + j] = v;
            }
        }
        __syncthreads();  // protect hid before next chunk
    }
}

// ---------------- graph max pooling over node_emb cols 0..351 ----------------
__device__ __forceinline__ unsigned fmap(float v) {
    unsigned u = __float_as_uint(v);
    return (u & 0x80000000u) ? ~u : (u | 0x80000000u);
}

__global__ __launch_bounds__(384) void k_colmax(const float* __restrict__ out, unsigned* __restrict__ gmax) {
    int c = threadIdx.x;
    if (c >= 352) return;
    float m = -1e30f;
    for (int n = blockIdx.x; n < N_NODES; n += gridDim.x)
        m = fmaxf(m, out[(size_t)n * 704 + c]);
    atomicMax(gmax + c, fmap(m));
}

__global__ __launch_bounds__(384) void k_bcast(const unsigned* __restrict__ gmax, float* __restrict__ out) {
    int c = threadIdx.x;
    if (c >= 352) return;
    unsigned u = gmax[c];
    u = (u & 0x80000000u) ? (u ^ 0x80000000u) : ~u;
    float v = __uint_as_float(u);
    for (int n = blockIdx.x; n < N_NODES; n += gridDim.x)
        out[(size_t)n * 704 + 352 + c] = v;
}

// ---------------- host launcher ----------------
extern "C" void kernel_launch(void* const* d_in, const int* in_sizes, int n_in,
                              void* d_out, int out_size, void* d_ws, size_t ws_size,
                              hipStream_t stream)
{
    (void)in_sizes; (void)n_in; (void)out_size; (void)ws_size;
    const float* feat     = (const float*)d_in[0];
    const float* att_rc   = (const float*)d_in[1];
    const float* att_rp   = (const float*)d_in[2];
    const float* type_emb = (const float*)d_in[3];
    const float* rid_emb  = (const float*)d_in[4];
    const float* rc_W     = (const float*)d_in[5];
    const float* rc_b     = (const float*)d_in[6];
    const float* rp_W     = (const float*)d_in[7];
    const float* rp_b     = (const float*)d_in[8];
    const float* fe_W1    = (const float*)d_in[9];
    const float* fe_b1    = (const float*)d_in[10];
    const float* fe_W2    = (const float*)d_in[11];
    const float* fe_b2    = (const float*)d_in[12];
    const float* W_ni     = (const float*)d_in[13];
    const float* W_nj     = (const float*)d_in[14];
    const float* W_fij    = (const float*)d_in[15];
    const float* W_node   = (const float*)d_in[16];
    const float* b_node   = (const float*)d_in[17];
    const float* attn     = (const float*)d_in[18];
    const float* mlp_W1   = (const float*)d_in[19];
    const float* mlp_b1   = (const float*)d_in[20];
    const float* mlp_W2   = (const float*)d_in[21];
    const float* mlp_b2   = (const float*)d_in[22];
    const int* src   = (const int*)d_in[23];
    const int* dst   = (const int*)d_in[24];
    const int* etype = (const int*)d_in[25];
    const int* erid  = (const int*)d_in[26];
    float* out = (float*)d_out;

    // Workspace layout (byte cursor, all chunks 16B aligned).
    char* cur = (char*)d_ws;
    auto alloc = [&](size_t bytes) { char* p = cur; cur += (bytes + 15) & ~(size_t)15; return p; };
    float* h_a   = (float*)alloc((size_t)N_NODES * 64 * 4);
    float* h_b   = (float*)alloc((size_t)N_NODES * 64 * 4);
    bf16_t* s    = (bf16_t*)alloc((size_t)N_NODES * 384 * 2);
    float* ev    = (float*)alloc((size_t)N_EDGES * 2 * 4);
    float* agg   = (float*)alloc((size_t)N_NODES * 128 * 4);
    int* deg     = (int*)alloc((size_t)N_NODES * 4);
    int* rowptr  = (int*)alloc((size_t)(N_NODES + 1) * 4);
    int* cursor  = (int*)alloc((size_t)N_NODES * 4);
    int* eidx    = (int*)alloc((size_t)N_EDGES * 4);
    int* src_s   = (int*)alloc((size_t)N_EDGES * 4);
    int* dst_s   = (int*)alloc((size_t)N_EDGES * 4);
    int* etype_s = (int*)alloc((size_t)N_EDGES * 4);
    int* erid_s  = (int*)alloc((size_t)N_EDGES * 4);
    float* rc_s  = (float*)alloc((size_t)N_EDGES * 2 * 4);
    float* rp_s  = (float*)alloc((size_t)N_EDGES * 3 * 4);
    int* bsum    = (int*)alloc(64 * 4);
    int* boff    = (int*)alloc(64 * 4);
    unsigned* gmax = (unsigned*)alloc(352 * 4);

    const int NB = (N_NODES + 1023) / 1024;  // 49

    k_zero32<<<(N_NODES + 255) / 256, 256, 0, stream>>>((unsigned*)deg, N_NODES);
    k_zero32<<<2, 256, 0, stream>>>(gmax, 352);
    k_hist<<<N_EDGES / 256, 256, 0, stream>>>(dst, deg);
    k_scan1<<<NB, 1024, 0, stream>>>(deg, rowptr, bsum);
    k_scan2<<<1, 64, 0, stream>>>(bsum, boff, NB);
    k_scan3<<<NB, 1024, 0, stream>>>(rowptr, boff);
    k_copy<<<(N_NODES + 255) / 256, 256, 0, stream>>>(rowptr, cursor);
    k_scatter<<<N_EDGES / 256, 256, 0, stream>>>(dst, cursor, eidx);
    k_sortgather<<<N_EDGES / 256, 256, 0, stream>>>(eidx, src, dst, etype, erid, att_rc, att_rp,
                                                    src_s, dst_s, etype_s, erid_s, rc_s, rp_s);
    k_fe<<<N_NODES / 4, 256, 0, stream>>>(feat, fe_W1, fe_b1, fe_W2, fe_b2, h_a, out);

    float* hc = h_a;
    float* hn = h_b;
    for (int l = 0; l < NLAYER; l++) {
        k_node3<<<dim3(768, 3), 128, 0, stream>>>(hc, W_ni + l * 64 * 128, W_nj + l * 64 * 128,
                                                  W_node + l * 64 * 128, b_node + l * 128, s);
        k_edge<<<1280, 256, 0, stream>>>(s, W_fij + l * 64 * 128, attn + l * 128,
                                         type_emb, rid_emb, rc_W, rc_b, rp_W, rp_b,
                                         rc_s, rp_s, etype_s, erid_s, src_s, dst_s, ev);
        k_soft_agg<<<4096, 256, 0, stream>>>(rowptr, src_s, ev, s, agg);
        k_mlp<<<1024, 128, 0, stream>>>(agg, mlp_W1 + l * 128 * 128, mlp_b1 + l * 128,
                                        mlp_W2 + l * 128 * 64, mlp_b2 + l * 64,
                                        hc, hn, out, 32 + 64 * (l + 1));
        float* tmp = hc; hc = hn; hn = tmp;
    }
    k_colmax<<<512, 384, 0, stream>>>(out, gmax);
    k_bcast<<<512, 384, 0, stream>>>(gmax, out);
}

// Round 3
// 2410.097 us; speedup vs baseline: 1.5666x; 1.5644x over previous
//
#include <hip/hip_runtime.h>
#include <math.h>

// Problem constants (fixed by the reference).
#define N_NODES 50000
#define N_EDGES 640000   // divisible by 64 (10000 tiles) and 256
#define NLAYER  4

typedef unsigned short bf16_t;

__device__ __forceinline__ float gelu_f(float x) {
    // jax.nn.gelu default approximate=True (tanh form)
    return 0.5f * x * (1.0f + tanhf(0.7978845608028654f * (x + 0.044715f * x * x * x)));
}

__device__ __forceinline__ bf16_t f2bf(float f) {
    unsigned u = __float_as_uint(f);
    unsigned r = (u + 0x7FFFu + ((u >> 16) & 1u)) >> 16;   // RNE
    return (bf16_t)r;
}
__device__ __forceinline__ float bf2f(bf16_t h) { return __uint_as_float(((unsigned)h) << 16); }
__device__ __forceinline__ float bfl(unsigned x) { return __uint_as_float(x << 16); }
__device__ __forceinline__ float bfh(unsigned x) { return __uint_as_float(x & 0xFFFF0000u); }

// ---------------- CSR build (counting sort by dst) ----------------
__global__ void k_zero32(unsigned* p, int n) {
    int i = blockIdx.x * 256 + threadIdx.x;
    if (i < n) p[i] = 0u;
}

__global__ void k_hist(const int* __restrict__ dst, int* __restrict__ deg) {
    int i = blockIdx.x * 256 + threadIdx.x;
    if (i < N_EDGES) atomicAdd(&deg[dst[i]], 1);
}

__global__ void k_scan1(const int* __restrict__ deg, int* __restrict__ rowptr, int* __restrict__ bsum) {
    __shared__ int sd[1024];
    int gi = blockIdx.x * 1024 + threadIdx.x;
    int v = (gi < N_NODES) ? deg[gi] : 0;
    sd[threadIdx.x] = v;
    __syncthreads();
    for (int off = 1; off < 1024; off <<= 1) {
        int t2 = (threadIdx.x >= (unsigned)off) ? sd[threadIdx.x - off] : 0;
        __syncthreads();
        sd[threadIdx.x] += t2;
        __syncthreads();
    }
    if (gi < N_NODES) rowptr[gi] = sd[threadIdx.x] - v;  // block-local exclusive
    if (threadIdx.x == 1023) bsum[blockIdx.x] = sd[1023];
}

__global__ void k_scan2(const int* __restrict__ bsum, int* __restrict__ boff, int nb) {
    if (threadIdx.x == 0 && blockIdx.x == 0) {
        int run = 0;
        for (int b = 0; b < nb; b++) { boff[b] = run; run += bsum[b]; }
    }
}

__global__ void k_scan3(int* __restrict__ rowptr, const int* __restrict__ boff) {
    int gi = blockIdx.x * 1024 + threadIdx.x;
    if (gi < N_NODES) rowptr[gi] += boff[blockIdx.x];
    if (gi == 0) rowptr[N_NODES] = N_EDGES;
}

__global__ void k_copy(const int* __restrict__ a, int* __restrict__ b) {
    int i = blockIdx.x * 256 + threadIdx.x;
    if (i < N_NODES) b[i] = a[i];
}

__global__ void k_scatter(const int* __restrict__ dst, int* __restrict__ cursor, int* __restrict__ eidx) {
    int i = blockIdx.x * 256 + threadIdx.x;
    if (i < N_EDGES) {
        int p = atomicAdd(&cursor[dst[i]], 1);
        eidx[p] = i;
    }
}

// Gather all per-edge fields into dst-sorted order so downstream kernels are linear.
__global__ void k_sortgather(
    const int* __restrict__ eidx, const int* __restrict__ src, const int* __restrict__ dst,
    const int* __restrict__ etype, const int* __restrict__ erid,
    const float* __restrict__ att_rc, const float* __restrict__ att_rp,
    int* __restrict__ src_s, int* __restrict__ dst_s,
    int* __restrict__ etype_s, int* __restrict__ erid_s,
    float* __restrict__ rc_s, float* __restrict__ rp_s)
{
    int i = blockIdx.x * 256 + threadIdx.x;
    if (i < N_EDGES) {
        int e = eidx[i];
        src_s[i] = src[e];
        dst_s[i] = dst[e];
        etype_s[i] = etype[e];
        erid_s[i] = erid[e];
        rc_s[2 * i] = att_rc[2 * e];
        rc_s[2 * i + 1] = att_rc[2 * e + 1];
        rp_s[3 * i] = att_rp[3 * e];
        rp_s[3 * i + 1] = att_rp[3 * e + 1];
        rp_s[3 * i + 2] = att_rp[3 * e + 2];
    }
}

// ---------------- feature encoder: h0 = gelu(feat@W1+b1)@W2+b2 ----------------
__global__ __launch_bounds__(256) void k_fe(
    const float* __restrict__ feat, const float* __restrict__ W1, const float* __restrict__ b1,
    const float* __restrict__ W2, const float* __restrict__ b2,
    float* __restrict__ h, float* __restrict__ out)
{
    __shared__ float hid[4][64];
    int w = threadIdx.x >> 6, lane = threadIdx.x & 63;
    int n = blockIdx.x * 4 + w;  // N divisible by 4
    float a = b1[lane];
#pragma unroll 8
    for (int k = 0; k < 32; k++) a = fmaf(feat[n * 32 + k], W1[k * 64 + lane], a);
    hid[w][lane] = gelu_f(a);
    __syncthreads();
    float o = b2[lane];
#pragma unroll 8
    for (int k = 0; k < 64; k++) o = fmaf(hid[w][k], W2[k * 64 + lane], o);
    h[n * 64 + lane] = o;
    out[n * 704 + 32 + lane] = o;
    if (lane < 32) out[n * 704 + lane] = feat[n * 32 + lane];
}

// ---------------- s = h @ [W_ni | W_nj | W_node(+b)]  -> [N,384] bf16 ----------------
__global__ __launch_bounds__(128) void k_node3(
    const float* __restrict__ h, const float* __restrict__ Wni,
    const float* __restrict__ Wnj, const float* __restrict__ Wnode,
    const float* __restrict__ bnode, bf16_t* __restrict__ s)
{
    int j = threadIdx.x;
    int c = blockIdx.y;
    const float* W = (c == 0) ? Wni : (c == 1) ? Wnj : Wnode;
    float bias = (c == 2) ? bnode[j] : 0.0f;
    for (int chunk = blockIdx.x; chunk < N_NODES / 8; chunk += gridDim.x) {
        int n0 = chunk * 8;
        float acc[8];
#pragma unroll
        for (int r = 0; r < 8; r++) acc[r] = bias;
        for (int k = 0; k < 64; k += 4) {
            float w0 = W[(k + 0) * 128 + j];
            float w1 = W[(k + 1) * 128 + j];
            float w2 = W[(k + 2) * 128 + j];
            float w3 = W[(k + 3) * 128 + j];
#pragma unroll
            for (int r = 0; r < 8; r++) {
                const float4 hv = *(const float4*)(h + (n0 + r) * 64 + k);
                acc[r] = fmaf(hv.x, w0, fmaf(hv.y, w1, fmaf(hv.z, w2, fmaf(hv.w, w3, acc[r]))));
            }
        }
#pragma unroll
        for (int r = 0; r < 8; r++) s[(size_t)(n0 + r) * 384 + c * 128 + j] = f2bf(acc[r]);
    }
}

// ---------------- fused edge kernel (dst-sorted order) ----------------
// Tile: 64 edges x 128 cols, K=64. 256 threads = 16tx x 16ty; micro-tile 4 edges x 8 cols.
// Gathers hoisted ABOVE the K-loop so gather latency overlaps GEMM compute.
__global__ __launch_bounds__(256) void k_edge(
    const bf16_t* __restrict__ s, const float* __restrict__ Wfij,
    const float* __restrict__ attn,
    const float* __restrict__ type_emb, const float* __restrict__ rid_emb,
    const float* __restrict__ rcW, const float* __restrict__ rcb,
    const float* __restrict__ rpW, const float* __restrict__ rpb,
    const float* __restrict__ rc_s, const float* __restrict__ rp_s,
    const int* __restrict__ etype_s, const int* __restrict__ erid_s,
    const int* __restrict__ src_s, const int* __restrict__ dst_s,
    float* __restrict__ evals)
{
    __shared__ __align__(16) float efT[64 * 68];  // [k][edge], padded stride
    const int t = threadIdx.x;
    const int tx = t & 15, ty = t >> 4;
    const int j0 = tx * 8, m0 = ty * 4;
    const int eb = blockIdx.x * 64;

    // Issue the epilogue gathers FIRST: 2 int4 index loads + 8 uint4 row-slice gathers.
    const int4 s4 = *(const int4*)(src_s + eb + m0);
    const int4 d4 = *(const int4*)(dst_s + eb + m0);
    uint4 U[4], V[4];
    {
        const int si[4] = {s4.x, s4.y, s4.z, s4.w};
        const int di[4] = {d4.x, d4.y, d4.z, d4.w};
#pragma unroll
        for (int m = 0; m < 4; m++) {
            U[m] = *(const uint4*)(s + (size_t)si[m] * 384 + j0);
            V[m] = *(const uint4*)(s + (size_t)di[m] * 384 + 128 + j0);
        }
    }

    // Phase A: edge embedding into LDS. Each thread: one edge (t&63), 16 k's.
    {
        int e_local = t & 63;
        int kg = (t >> 6) * 16;
        int i = eb + e_local;
        int et = etype_s[i] * 64, er = erid_s[i] * 64;
        float rc0 = rc_s[i * 2 + 0], rc1 = rc_s[i * 2 + 1];
        float rp0 = rp_s[i * 3 + 0], rp1 = rp_s[i * 3 + 1], rp2 = rp_s[i * 3 + 2];
#pragma unroll
        for (int kk = 0; kk < 16; kk++) {
            int k = kg + kk;
            float v = type_emb[et + k] + rid_emb[er + k] + rcb[k] + rpb[k];
            v = fmaf(rc0, rcW[k], v);
            v = fmaf(rc1, rcW[64 + k], v);
            v = fmaf(rp0, rpW[k], v);
            v = fmaf(rp1, rpW[64 + k], v);
            v = fmaf(rp2, rpW[128 + k], v);
            efT[k * 68 + e_local] = v;
        }
    }
    float areg[8];
#pragma unroll
    for (int jj = 0; jj < 8; jj++) areg[jj] = attn[j0 + jj];
    __syncthreads();

    // Phase B: register-tiled GEMM fij = efT^T @ W_fij (4 edges x 8 cols per thread)
    float acc[4][8];
#pragma unroll
    for (int m = 0; m < 4; m++)
#pragma unroll
        for (int jj = 0; jj < 8; jj++) acc[m][jj] = 0.f;
    for (int k = 0; k < 64; k++) {
        const float4 a = *(const float4*)&efT[k * 68 + m0];
        const float4 b0 = *(const float4*)(Wfij + k * 128 + j0);
        const float4 b1 = *(const float4*)(Wfij + k * 128 + j0 + 4);
        float am[4] = {a.x, a.y, a.z, a.w};
        float bj[8] = {b0.x, b0.y, b0.z, b0.w, b1.x, b1.y, b1.z, b1.w};
#pragma unroll
        for (int m = 0; m < 4; m++)
#pragma unroll
            for (int jj = 0; jj < 8; jj++)
                acc[m][jj] = fmaf(am[m], bj[jj], acc[m][jj]);
    }

    // Epilogue: + s_ni[src] + s_nj[dst] (bf16, pre-gathered), leaky_relu, dot attn, reduce
#pragma unroll
    for (int m = 0; m < 4; m++) {
        int i = eb + m0 + m;
        float uu[8] = {bfl(U[m].x), bfh(U[m].x), bfl(U[m].y), bfh(U[m].y),
                       bfl(U[m].z), bfh(U[m].z), bfl(U[m].w), bfh(U[m].w)};
        float vv[8] = {bfl(V[m].x), bfh(V[m].x), bfl(V[m].y), bfh(V[m].y),
                       bfl(V[m].z), bfh(V[m].z), bfl(V[m].w), bfh(V[m].w)};
        float p = 0.f;
#pragma unroll
        for (int jj = 0; jj < 8; jj++) {
            float f = acc[m][jj] + uu[jj] + vv[jj];
            f = (f >= 0.f) ? f : 0.2f * f;
            p = fmaf(f, areg[jj], p);
        }
        p += __shfl_xor(p, 1);
        p += __shfl_xor(p, 2);
        p += __shfl_xor(p, 4);
        if ((tx & 7) == 0) evals[i * 2 + (tx >> 3)] = p;  // head = tx>>3
    }
}

// ---------------- per-dst softmax + aggregation (wave per node, sorted CSR) ----------------
// Lane l accumulates output features {2l, 2l+1}: head0 = lanes 0..31, head1 = lanes 32..63.
// One uint (2 bf16) per lane per edge -> full 256B wave request; depth-2 pipelined gather.
__global__ __launch_bounds__(256) void k_soft_agg(
    const int* __restrict__ rowptr, const int* __restrict__ src_s,
    const float* __restrict__ evals, const bf16_t* __restrict__ s,
    float* __restrict__ agg)
{
    int lane = threadIdx.x & 63;
    int wid = (blockIdx.x * 256 + threadIdx.x) >> 6;
    int nw = (gridDim.x * 256) >> 6;
    const bool h1 = (lane >= 32);
    for (int n = wid; n < N_NODES; n += nw) {
        int r0 = rowptr[n], r1 = rowptr[n + 1];
        float2* aout = (float2*)(agg + (size_t)n * 128 + 2 * lane);
        if (r0 == r1) { *aout = make_float2(0.f, 0.f); continue; }
        float m0 = -1e30f, m1 = -1e30f;
        for (int i = r0 + lane; i < r1; i += 64) {
            m0 = fmaxf(m0, evals[2 * i]);
            m1 = fmaxf(m1, evals[2 * i + 1]);
        }
#pragma unroll
        for (int off = 1; off < 64; off <<= 1) {
            m0 = fmaxf(m0, __shfl_xor(m0, off));
            m1 = fmaxf(m1, __shfl_xor(m1, off));
        }
        float z0 = 0.f, z1 = 0.f;
        for (int i = r0 + lane; i < r1; i += 64) {
            z0 += expf(evals[2 * i] - m0);
            z1 += expf(evals[2 * i + 1] - m1);
        }
#pragma unroll
        for (int off = 1; off < 64; off <<= 1) {
            z0 += __shfl_xor(z0, off);
            z1 += __shfl_xor(z1, off);
        }
        float rz0 = 1.f / z0, rz1 = 1.f / z1;
        float acc0 = 0.f, acc1 = 0.f;
        // depth-2 software pipeline over the (wave-uniform) edge loop
        unsigned cur = *(const unsigned*)(s + (size_t)src_s[r0] * 384 + 256 + 2 * lane);
        float e0 = evals[2 * r0], e1 = evals[2 * r0 + 1];
        for (int i = r0; i < r1; i++) {
            unsigned nxt = 0u;
            float ne0 = 0.f, ne1 = 0.f;
            if (i + 1 < r1) {
                nxt = *(const unsigned*)(s + (size_t)src_s[i + 1] * 384 + 256 + 2 * lane);
                ne0 = evals[2 * i + 2];
                ne1 = evals[2 * i + 3];
            }
            float w = h1 ? expf(e1 - m1) * rz1 : expf(e0 - m0) * rz0;
            acc0 = fmaf(w, bfl(cur), acc0);
            acc1 = fmaf(w, bfh(cur), acc1);
            cur = nxt; e0 = ne0; e1 = ne1;
        }
        *aout = make_float2(acc0, acc1);
    }
}

// ---------------- node MLP + residual: h' = gelu(agg@W1+b1)@W2+b2 + h ----------------
__global__ __launch_bounds__(128) void k_mlp(
    const float* __restrict__ agg, const float* __restrict__ W1, const float* __restrict__ b1,
    const float* __restrict__ W2, const float* __restrict__ b2,
    const float* __restrict__ hin, float* __restrict__ hout, float* __restrict__ out, int col0)
{
    __shared__ __align__(16) float hid[8 * 128];
    int j = threadIdx.x;
    for (int chunk = blockIdx.x; chunk < N_NODES / 8; chunk += gridDim.x) {
        int n0 = chunk * 8;
        float acc[8];
        float bb = b1[j];
#pragma unroll
        for (int r = 0; r < 8; r++) acc[r] = bb;
        for (int k = 0; k < 128; k += 4) {
            float w0 = W1[(k + 0) * 128 + j];
            float w1 = W1[(k + 1) * 128 + j];
            float w2 = W1[(k + 2) * 128 + j];
            float w3 = W1[(k + 3) * 128 + j];
#pragma unroll
            for (int r = 0; r < 8; r++) {
                const float4 av = *(const float4*)(agg + (size_t)(n0 + r) * 128 + k);
                acc[r] = fmaf(av.x, w0, fmaf(av.y, w1, fmaf(av.z, w2, fmaf(av.w, w3, acc[r]))));
            }
        }
#pragma unroll
        for (int r = 0; r < 8; r++) hid[r * 128 + j] = gelu_f(acc[r]);
        __syncthreads();
        if (j < 64) {
            float acc2[8];
            float bb2 = b2[j];
#pragma unroll
            for (int r = 0; r < 8; r++) acc2[r] = bb2;
            for (int k = 0; k < 128; k += 4) {
                float w0 = W2[(k + 0) * 64 + j];
                float w1 = W2[(k + 1) * 64 + j];
                float w2 = W2[(k + 2) * 64 + j];
                float w3 = W2[(k + 3) * 64 + j];
#pragma unroll
                for (int r = 0; r < 8; r++) {
                    const float4 hv = *(const float4*)&hid[r * 128 + k];
                    acc2[r] = fmaf(hv.x, w0, fmaf(hv.y, w1, fmaf(hv.z, w2, fmaf(hv.w, w3, acc2[r]))));
                }
            }
#pragma unroll
            for (int r = 0; r < 8; r++) {
                float v = acc2[r] + hin[(n0 + r) * 64 + j];
                hout[(n0 + r) * 64 + j] = v;
                out[(size_t)(n0 + r) * 704 + col0 + j] = v;
            }
        }
        __syncthreads();  // protect hid before next chunk
    }
}

// ---------------- graph max pooling over node_emb cols 0..351 ----------------
__device__ __forceinline__ unsigned fmap(float v) {
    unsigned u = __float_as_uint(v);
    return (u & 0x80000000u) ? ~u : (u | 0x80000000u);
}

__global__ __launch_bounds__(384) void k_colmax(const float* __restrict__ out, unsigned* __restrict__ gmax) {
    int c = threadIdx.x;
    if (c >= 352) return;
    float m = -1e30f;
    for (int n = blockIdx.x; n < N_NODES; n += gridDim.x)
        m = fmaxf(m, out[(size_t)n * 704 + c]);
    atomicMax(gmax + c, fmap(m));
}

__global__ __launch_bounds__(384) void k_bcast(const unsigned* __restrict__ gmax, float* __restrict__ out) {
    int c = threadIdx.x;
    if (c >= 352) return;
    unsigned u = gmax[c];
    u = (u & 0x80000000u) ? (u ^ 0x80000000u) : ~u;
    float v = __uint_as_float(u);
    for (int n = blockIdx.x; n < N_NODES; n += gridDim.x)
        out[(size_t)n * 704 + 352 + c] = v;
}

// ---------------- host launcher ----------------
extern "C" void kernel_launch(void* const* d_in, const int* in_sizes, int n_in,
                              void* d_out, int out_size, void* d_ws, size_t ws_size,
                              hipStream_t stream)
{
    (void)in_sizes; (void)n_in; (void)out_size; (void)ws_size;
    const float* feat     = (const float*)d_in[0];
    const float* att_rc   = (const float*)d_in[1];
    const float* att_rp   = (const float*)d_in[2];
    const float* type_emb = (const float*)d_in[3];
    const float* rid_emb  = (const float*)d_in[4];
    const float* rc_W     = (const float*)d_in[5];
    const float* rc_b     = (const float*)d_in[6];
    const float* rp_W     = (const float*)d_in[7];
    const float* rp_b     = (const float*)d_in[8];
    const float* fe_W1    = (const float*)d_in[9];
    const float* fe_b1    = (const float*)d_in[10];
    const float* fe_W2    = (const float*)d_in[11];
    const float* fe_b2    = (const float*)d_in[12];
    const float* W_ni     = (const float*)d_in[13];
    const float* W_nj     = (const float*)d_in[14];
    const float* W_fij    = (const float*)d_in[15];
    const float* W_node   = (const float*)d_in[16];
    const float* b_node   = (const float*)d_in[17];
    const float* attn     = (const float*)d_in[18];
    const float* mlp_W1   = (const float*)d_in[19];
    const float* mlp_b1   = (const float*)d_in[20];
    const float* mlp_W2   = (const float*)d_in[21];
    const float* mlp_b2   = (const float*)d_in[22];
    const int* src   = (const int*)d_in[23];
    const int* dst   = (const int*)d_in[24];
    const int* etype = (const int*)d_in[25];
    const int* erid  = (const int*)d_in[26];
    float* out = (float*)d_out;

    // Workspace layout (byte cursor, all chunks 16B aligned).
    char* cur = (char*)d_ws;
    auto alloc = [&](size_t bytes) { char* p = cur; cur += (bytes + 15) & ~(size_t)15; return p; };
    float* h_a   = (float*)alloc((size_t)N_NODES * 64 * 4);
    float* h_b   = (float*)alloc((size_t)N_NODES * 64 * 4);
    bf16_t* s    = (bf16_t*)alloc((size_t)N_NODES * 384 * 2);
    float* ev    = (float*)alloc((size_t)N_EDGES * 2 * 4);
    float* agg   = (float*)alloc((size_t)N_NODES * 128 * 4);
    int* deg     = (int*)alloc((size_t)N_NODES * 4);
    int* rowptr  = (int*)alloc((size_t)(N_NODES + 1) * 4);
    int* cursor  = (int*)alloc((size_t)N_NODES * 4);
    int* eidx    = (int*)alloc((size_t)N_EDGES * 4);
    int* src_s   = (int*)alloc((size_t)N_EDGES * 4);
    int* dst_s   = (int*)alloc((size_t)N_EDGES * 4);
    int* etype_s = (int*)alloc((size_t)N_EDGES * 4);
    int* erid_s  = (int*)alloc((size_t)N_EDGES * 4);
    float* rc_s  = (float*)alloc((size_t)N_EDGES * 2 * 4);
    float* rp_s  = (float*)alloc((size_t)N_EDGES * 3 * 4);
    int* bsum    = (int*)alloc(64 * 4);
    int* boff    = (int*)alloc(64 * 4);
    unsigned* gmax = (unsigned*)alloc(352 * 4);

    const int NB = (N_NODES + 1023) / 1024;  // 49

    k_zero32<<<(N_NODES + 255) / 256, 256, 0, stream>>>((unsigned*)deg, N_NODES);
    k_zero32<<<2, 256, 0, stream>>>(gmax, 352);
    k_hist<<<N_EDGES / 256, 256, 0, stream>>>(dst, deg);
    k_scan1<<<NB, 1024, 0, stream>>>(deg, rowptr, bsum);
    k_scan2<<<1, 64, 0, stream>>>(bsum, boff, NB);
    k_scan3<<<NB, 1024, 0, stream>>>(rowptr, boff);
    k_copy<<<(N_NODES + 255) / 256, 256, 0, stream>>>(rowptr, cursor);
    k_scatter<<<N_EDGES / 256, 256, 0, stream>>>(dst, cursor, eidx);
    k_sortgather<<<N_EDGES / 256, 256, 0, stream>>>(eidx, src, dst, etype, erid, att_rc, att_rp,
                                                    src_s, dst_s, etype_s, erid_s, rc_s, rp_s);
    k_fe<<<N_NODES / 4, 256, 0, stream>>>(feat, fe_W1, fe_b1, fe_W2, fe_b2, h_a, out);

    float* hc = h_a;
    float* hn = h_b;
    for (int l = 0; l < NLAYER; l++) {
        k_node3<<<dim3(768, 3), 128, 0, stream>>>(hc, W_ni + l * 64 * 128, W_nj + l * 64 * 128,
                                                  W_node + l * 64 * 128, b_node + l * 128, s);
        k_edge<<<N_EDGES / 64, 256, 0, stream>>>(s, W_fij + l * 64 * 128, attn + l * 128,
                                                 type_emb, rid_emb, rc_W, rc_b, rp_W, rp_b,
                                                 rc_s, rp_s, etype_s, erid_s, src_s, dst_s, ev);
        k_soft_agg<<<4096, 256, 0, stream>>>(rowptr, src_s, ev, s, agg);
        k_mlp<<<1024, 128, 0, stream>>>(agg, mlp_W1 + l * 128 * 128, mlp_b1 + l * 128,
                                        mlp_W2 + l * 128 * 64, mlp_b2 + l * 64,
                                        hc, hn, out, 32 + 64 * (l + 1));
        float* tmp = hc; hc = hn; hn = tmp;
    }
    k_colmax<<<512, 384, 0, stream>>>(out, gmax);
    k_bcast<<<512, 384, 0, stream>>>(gmax, out);
}

// Round 4
// 1780.444 us; speedup vs baseline: 2.1207x; 1.3536x over previous
//
#include <hip/hip_runtime.h>
#include <math.h>

// Problem constants (fixed by the reference).
#define N_NODES 50000
#define N_EDGES 640000   // divisible by 32 (20000 tiles) and 256
#define NLAYER  4

typedef unsigned short bf16_t;
typedef __attribute__((ext_vector_type(8))) short s16x8;   // 8 bf16 = 4 VGPR (MFMA A/B frag)
typedef __attribute__((ext_vector_type(4))) float f32x4;   // MFMA C/D frag

__device__ __forceinline__ float gelu_f(float x) {
    return 0.5f * x * (1.0f + tanhf(0.7978845608028654f * (x + 0.044715f * x * x * x)));
}

__device__ __forceinline__ bf16_t f2bf(float f) {
    unsigned u = __float_as_uint(f);
    unsigned r = (u + 0x7FFFu + ((u >> 16) & 1u)) >> 16;   // RNE
    return (bf16_t)r;
}
__device__ __forceinline__ float bf2f(bf16_t h) { return __uint_as_float(((unsigned)h) << 16); }
__device__ __forceinline__ float bfl(unsigned x) { return __uint_as_float(x << 16); }
__device__ __forceinline__ float bfh(unsigned x) { return __uint_as_float(x & 0xFFFF0000u); }

// ---------------- CSR build (counting sort by dst) ----------------
__global__ void k_zero32(unsigned* p, int n) {
    int i = blockIdx.x * 256 + threadIdx.x;
    if (i < n) p[i] = 0u;
}

__global__ void k_hist(const int* __restrict__ dst, int* __restrict__ deg) {
    int i = blockIdx.x * 256 + threadIdx.x;
    if (i < N_EDGES) atomicAdd(&deg[dst[i]], 1);
}

__global__ void k_scan1(const int* __restrict__ deg, int* __restrict__ rowptr, int* __restrict__ bsum) {
    __shared__ int sd[1024];
    int gi = blockIdx.x * 1024 + threadIdx.x;
    int v = (gi < N_NODES) ? deg[gi] : 0;
    sd[threadIdx.x] = v;
    __syncthreads();
    for (int off = 1; off < 1024; off <<= 1) {
        int t2 = (threadIdx.x >= (unsigned)off) ? sd[threadIdx.x - off] : 0;
        __syncthreads();
        sd[threadIdx.x] += t2;
        __syncthreads();
    }
    if (gi < N_NODES) rowptr[gi] = sd[threadIdx.x] - v;  // block-local exclusive
    if (threadIdx.x == 1023) bsum[blockIdx.x] = sd[1023];
}

__global__ void k_scan2(const int* __restrict__ bsum, int* __restrict__ boff, int nb) {
    if (threadIdx.x == 0 && blockIdx.x == 0) {
        int run = 0;
        for (int b = 0; b < nb; b++) { boff[b] = run; run += bsum[b]; }
    }
}

__global__ void k_scan3(int* __restrict__ rowptr, const int* __restrict__ boff) {
    int gi = blockIdx.x * 1024 + threadIdx.x;
    if (gi < N_NODES) rowptr[gi] += boff[blockIdx.x];
    if (gi == 0) rowptr[N_NODES] = N_EDGES;
}

__global__ void k_copy(const int* __restrict__ a, int* __restrict__ b) {
    int i = blockIdx.x * 256 + threadIdx.x;
    if (i < N_NODES) b[i] = a[i];
}

__global__ void k_scatter(const int* __restrict__ dst, int* __restrict__ cursor, int* __restrict__ eidx) {
    int i = blockIdx.x * 256 + threadIdx.x;
    if (i < N_EDGES) {
        int p = atomicAdd(&cursor[dst[i]], 1);
        eidx[p] = i;
    }
}

// Gather all per-edge fields into dst-sorted order so downstream kernels are linear.
__global__ void k_sortgather(
    const int* __restrict__ eidx, const int* __restrict__ src, const int* __restrict__ dst,
    const int* __restrict__ etype, const int* __restrict__ erid,
    const float* __restrict__ att_rc, const float* __restrict__ att_rp,
    int* __restrict__ src_s, int* __restrict__ dst_s,
    int* __restrict__ etype_s, int* __restrict__ erid_s,
    float* __restrict__ rc_s, float* __restrict__ rp_s)
{
    int i = blockIdx.x * 256 + threadIdx.x;
    if (i < N_EDGES) {
        int e = eidx[i];
        src_s[i] = src[e];
        dst_s[i] = dst[e];
        etype_s[i] = etype[e];
        erid_s[i] = erid[e];
        rc_s[2 * i] = att_rc[2 * e];
        rc_s[2 * i + 1] = att_rc[2 * e + 1];
        rp_s[3 * i] = att_rp[3 * e];
        rp_s[3 * i + 1] = att_rp[3 * e + 1];
        rp_s[3 * i + 2] = att_rp[3 * e + 2];
    }
}

// W_fij [L][64][128] fp32 -> WT [L][128][64] bf16 (transposed, k-contiguous per wcol)
__global__ void k_wprep(const float* __restrict__ W, bf16_t* __restrict__ WT) {
    int idx = blockIdx.x * 256 + threadIdx.x;   // 4*64*128 = 32768
    if (idx < NLAYER * 64 * 128) {
        int l = idx >> 13, rem = idx & 8191;
        int n = rem >> 6, k = rem & 63;
        WT[idx] = f2bf(W[l * 8192 + k * 128 + n]);
    }
}

// ---------------- feature encoder: h0 = gelu(feat@W1+b1)@W2+b2 ----------------
__global__ __launch_bounds__(256) void k_fe(
    const float* __restrict__ feat, const float* __restrict__ W1, const float* __restrict__ b1,
    const float* __restrict__ W2, const float* __restrict__ b2,
    float* __restrict__ h, float* __restrict__ out)
{
    __shared__ float hid[4][64];
    int w = threadIdx.x >> 6, lane = threadIdx.x & 63;
    int n = blockIdx.x * 4 + w;  // N divisible by 4
    float a = b1[lane];
#pragma unroll 8
    for (int k = 0; k < 32; k++) a = fmaf(feat[n * 32 + k], W1[k * 64 + lane], a);
    hid[w][lane] = gelu_f(a);
    __syncthreads();
    float o = b2[lane];
#pragma unroll 8
    for (int k = 0; k < 64; k++) o = fmaf(hid[w][k], W2[k * 64 + lane], o);
    h[n * 64 + lane] = o;
    out[n * 704 + 32 + lane] = o;
    if (lane < 32) out[n * 704 + lane] = feat[n * 32 + lane];
}

// ---------------- s = h @ [W_ni | W_nj | W_node(+b)]  -> [N,384] bf16 ----------------
__global__ __launch_bounds__(128) void k_node3(
    const float* __restrict__ h, const float* __restrict__ Wni,
    const float* __restrict__ Wnj, const float* __restrict__ Wnode,
    const float* __restrict__ bnode, bf16_t* __restrict__ s)
{
    int j = threadIdx.x;
    int c = blockIdx.y;
    const float* W = (c == 0) ? Wni : (c == 1) ? Wnj : Wnode;
    float bias = (c == 2) ? bnode[j] : 0.0f;
    for (int chunk = blockIdx.x; chunk < N_NODES / 8; chunk += gridDim.x) {
        int n0 = chunk * 8;
        float acc[8];
#pragma unroll
        for (int r = 0; r < 8; r++) acc[r] = bias;
        for (int k = 0; k < 64; k += 4) {
            float w0 = W[(k + 0) * 128 + j];
            float w1 = W[(k + 1) * 128 + j];
            float w2 = W[(k + 2) * 128 + j];
            float w3 = W[(k + 3) * 128 + j];
#pragma unroll
            for (int r = 0; r < 8; r++) {
                const float4 hv = *(const float4*)(h + (n0 + r) * 64 + k);
                acc[r] = fmaf(hv.x, w0, fmaf(hv.y, w1, fmaf(hv.z, w2, fmaf(hv.w, w3, acc[r]))));
            }
        }
#pragma unroll
        for (int r = 0; r < 8; r++) s[(size_t)(n0 + r) * 384 + c * 128 + j] = f2bf(acc[r]);
    }
}

// ---------------- fused edge kernel, MFMA version ----------------
// Per 32-edge tile: f^T[wcol][edge] = W_fij^T @ ef^T via mfma_f32_16x16x32_bf16.
// 4 waves: wave w -> edges (w&1)*16..+15, head w>>1 (64 wcols = 4 M-tiles).
// A = W^T frags (register-resident, loop-invariant). B = ef (bf16, LDS).
// C layout: col=lane&15 (edge), row=quad*4+reg (wcol). s_ni[src]+s_nj[dst]
// pre-summed into LDS bf16, read as ds_read_b64 in C layout.
__global__ __launch_bounds__(256) void k_edge(
    const bf16_t* __restrict__ s, const bf16_t* __restrict__ WT,
    const float* __restrict__ attn,
    const float* __restrict__ type_emb, const float* __restrict__ rid_emb,
    const float* __restrict__ rcW, const float* __restrict__ rcb,
    const float* __restrict__ rpW, const float* __restrict__ rpb,
    const float* __restrict__ rc_s, const float* __restrict__ rp_s,
    const int* __restrict__ etype_s, const int* __restrict__ erid_s,
    const int* __restrict__ src_s, const int* __restrict__ dst_s,
    float* __restrict__ evals)
{
    __shared__ __align__(16) bf16_t efA[32 * 72];    // [edge][k], pad 72 (144B rows, 16B-aligned)
    __shared__ __align__(16) bf16_t SND[32 * 136];   // [edge][col] = s_ni[src]+s_nj[dst], pad 136
    const int t = threadIdx.x;
    const int wave = t >> 6, lane = t & 63;
    const int l16 = lane & 15, quad = lane >> 4;
    const int eg = wave & 1, head = wave >> 1;

    // Loop-invariant: W^T fragments (A operand) + attn coefficients (C layout).
    s16x8 Aw[4][2];
    float4 att4[4];
#pragma unroll
    for (int mt = 0; mt < 4; mt++) {
        const bf16_t* wrow = WT + (head * 64 + mt * 16 + l16) * 64 + quad * 8;
        Aw[mt][0] = *(const s16x8*)(wrow);
        Aw[mt][1] = *(const s16x8*)(wrow + 32);
        att4[mt] = *(const float4*)(attn + head * 64 + mt * 16 + quad * 4);
    }

    for (int tile = blockIdx.x; tile < N_EDGES / 32; tile += gridDim.x) {
        const int eb = tile * 32;
        __syncthreads();  // previous tile's reads done before overwriting LDS
        {   // Phase A: edge embedding -> efA (each thread: 1 edge, 8 k's, bf16)
            int e = t & 31, kg = (t >> 5) * 8;
            int i = eb + e;
            int et = etype_s[i] * 64, er = erid_s[i] * 64;
            float rc0 = rc_s[i * 2 + 0], rc1 = rc_s[i * 2 + 1];
            float rp0 = rp_s[i * 3 + 0], rp1 = rp_s[i * 3 + 1], rp2 = rp_s[i * 3 + 2];
            bf16_t tmp[8];
#pragma unroll
            for (int kk = 0; kk < 8; kk++) {
                int k = kg + kk;
                float v = type_emb[et + k] + rid_emb[er + k] + rcb[k] + rpb[k];
                v = fmaf(rc0, rcW[k], v);
                v = fmaf(rc1, rcW[64 + k], v);
                v = fmaf(rp0, rpW[k], v);
                v = fmaf(rp1, rpW[64 + k], v);
                v = fmaf(rp2, rpW[128 + k], v);
                tmp[kk] = f2bf(v);
            }
            *(s16x8*)(&efA[e * 72 + kg]) = *(const s16x8*)tmp;
        }
        {   // Phase A2: SND = s_ni[src] + s_nj[dst] (bf16). 512 row-chunks, 2/thread.
#pragma unroll
            for (int j = 0; j < 2; j++) {
                int c = t * 2 + j;
                int e = c >> 4, p = c & 15;
                int i = eb + e;
                const uint4 U = *(const uint4*)(s + (size_t)src_s[i] * 384 + p * 8);
                const uint4 V = *(const uint4*)(s + (size_t)dst_s[i] * 384 + 128 + p * 8);
                bf16_t o[8];
                o[0] = f2bf(bfl(U.x) + bfl(V.x)); o[1] = f2bf(bfh(U.x) + bfh(V.x));
                o[2] = f2bf(bfl(U.y) + bfl(V.y)); o[3] = f2bf(bfh(U.y) + bfh(V.y));
                o[4] = f2bf(bfl(U.z) + bfl(V.z)); o[5] = f2bf(bfh(U.z) + bfh(V.z));
                o[6] = f2bf(bfl(U.w) + bfl(V.w)); o[7] = f2bf(bfh(U.w) + bfh(V.w));
                *(s16x8*)(&SND[e * 136 + p * 8]) = *(const s16x8*)o;
            }
        }
        __syncthreads();

        // MFMA: B frags = ef rows (edge = eg*16 + l16), K-steps k=quad*8+j (+32).
        const int e = eg * 16 + l16;
        const s16x8 B0 = *(const s16x8*)(&efA[e * 72 + quad * 8]);
        const s16x8 B1 = *(const s16x8*)(&efA[e * 72 + 32 + quad * 8]);
        f32x4 acc[4];
#pragma unroll
        for (int mt = 0; mt < 4; mt++) {
            f32x4 a = {0.f, 0.f, 0.f, 0.f};
            a = __builtin_amdgcn_mfma_f32_16x16x32_bf16(Aw[mt][0], B0, a, 0, 0, 0);
            a = __builtin_amdgcn_mfma_f32_16x16x32_bf16(Aw[mt][1], B1, a, 0, 0, 0);
            acc[mt] = a;
        }

        // Epilogue: f = acc + snd; leaky; dot attn; reduce over quads; store.
        float p = 0.f;
#pragma unroll
        for (int mt = 0; mt < 4; mt++) {
            const ushort4 sv = *(const ushort4*)(&SND[e * 136 + mt * 16 + quad * 4]);
            float f0 = acc[mt][0] + bf2f(sv.x);
            float f1 = acc[mt][1] + bf2f(sv.y);
            float f2 = acc[mt][2] + bf2f(sv.z);
            float f3 = acc[mt][3] + bf2f(sv.w);
            f0 = (f0 >= 0.f) ? f0 : 0.2f * f0;
            f1 = (f1 >= 0.f) ? f1 : 0.2f * f1;
            f2 = (f2 >= 0.f) ? f2 : 0.2f * f2;
            f3 = (f3 >= 0.f) ? f3 : 0.2f * f3;
            p = fmaf(f0, att4[mt].x, p);
            p = fmaf(f1, att4[mt].y, p);
            p = fmaf(f2, att4[mt].z, p);
            p = fmaf(f3, att4[mt].w, p);
        }
        p += __shfl_xor(p, 16);
        p += __shfl_xor(p, 32);
        if (quad == 0) evals[(eb + e) * 2 + head] = p;
    }
}

// ---------------- per-dst softmax + aggregation (wave per node, sorted CSR) ----------------
// Lane l: output features {2l, 2l+1}; head = l>=32. Batched (x8) gather pipeline.
__global__ __launch_bounds__(256) void k_soft_agg(
    const int* __restrict__ rowptr, const int* __restrict__ src_s,
    const float* __restrict__ evals, const bf16_t* __restrict__ s,
    float* __restrict__ agg)
{
    int lane = threadIdx.x & 63;
    int wid = (blockIdx.x * 256 + threadIdx.x) >> 6;
    int nw = (gridDim.x * 256) >> 6;
    const int h1 = (lane >= 32) ? 1 : 0;
    const int half = lane & 31;
    for (int n = wid; n < N_NODES; n += nw) {
        int r0 = rowptr[n], r1 = rowptr[n + 1];
        float2* aout = (float2*)(agg + (size_t)n * 128 + 2 * lane);
        if (r0 == r1) { *aout = make_float2(0.f, 0.f); continue; }
        // pass 1: per-head max (each half-wave covers its own head's evals)
        float mm = -1e30f;
        for (int i = r0 + half; i < r1; i += 32) mm = fmaxf(mm, evals[2 * i + h1]);
#pragma unroll
        for (int off = 1; off < 32; off <<= 1) mm = fmaxf(mm, __shfl_xor(mm, off));
        // pass 2: per-head denom
        float z = 0.f;
        for (int i = r0 + half; i < r1; i += 32) z += expf(evals[2 * i + h1] - mm);
#pragma unroll
        for (int off = 1; off < 32; off <<= 1) z += __shfl_xor(z, off);
        float rz = 1.f / z;
        // pass 3: weighted gather-sum, batched x8 to keep 8 gathers in flight
        float acc0 = 0.f, acc1 = 0.f;
        for (int i = r0; i < r1; i += 8) {
            int cnt = r1 - i;
            unsigned cc[8]; float ww[8];
#pragma unroll
            for (int j = 0; j < 8; j++) {
                if (j < cnt) {
                    cc[j] = *(const unsigned*)(s + (size_t)src_s[i + j] * 384 + 256 + 2 * lane);
                    ww[j] = expf(evals[2 * (i + j) + h1] - mm) * rz;
                } else { cc[j] = 0u; ww[j] = 0.f; }
            }
#pragma unroll
            for (int j = 0; j < 8; j++) {
                acc0 = fmaf(ww[j], bfl(cc[j]), acc0);
                acc1 = fmaf(ww[j], bfh(cc[j]), acc1);
            }
        }
        *aout = make_float2(acc0, acc1);
    }
}

// ---------------- node MLP + residual: h' = gelu(agg@W1+b1)@W2+b2 + h ----------------
__global__ __launch_bounds__(128) void k_mlp(
    const float* __restrict__ agg, const float* __restrict__ W1, const float* __restrict__ b1,
    const float* __restrict__ W2, const float* __restrict__ b2,
    const float* __restrict__ hin, float* __restrict__ hout, float* __restrict__ out, int col0)
{
    __shared__ __align__(16) float hid[8 * 128];
    int j = threadIdx.x;
    for (int chunk = blockIdx.x; chunk < N_NODES / 8; chunk += gridDim.x) {
        int n0 = chunk * 8;
        float acc[8];
        float bb = b1[j];
#pragma unroll
        for (int r = 0; r < 8; r++) acc[r] = bb;
        for (int k = 0; k < 128; k += 4) {
            float w0 = W1[(k + 0) * 128 + j];
            float w1 = W1[(k + 1) * 128 + j];
            float w2 = W1[(k + 2) * 128 + j];
            float w3 = W1[(k + 3) * 128 + j];
#pragma unroll
            for (int r = 0; r < 8; r++) {
                const float4 av = *(const float4*)(agg + (size_t)(n0 + r) * 128 + k);
                acc[r] = fmaf(av.x, w0, fmaf(av.y, w1, fmaf(av.z, w2, fmaf(av.w, w3, acc[r]))));
            }
        }
#pragma unroll
        for (int r = 0; r < 8; r++) hid[r * 128 + j] = gelu_f(acc[r]);
        __syncthreads();
        if (j < 64) {
            float acc2[8];
            float bb2 = b2[j];
#pragma unroll
            for (int r = 0; r < 8; r++) acc2[r] = bb2;
            for (int k = 0; k < 128; k += 4) {
                float w0 = W2[(k + 0) * 64 + j];
                float w1 = W2[(k + 1) * 64 + j];
                float w2 = W2[(k + 2) * 64 + j];
                float w3 = W2[(k + 3) * 64 + j];
#pragma unroll
                for (int r = 0; r < 8; r++) {
                    const float4 hv = *(const float4*)&hid[r * 128 + k];
                    acc2[r] = fmaf(hv.x, w0, fmaf(hv.y, w1, fmaf(hv.z, w2, fmaf(hv.w, w3, acc2[r]))));
                }
            }
#pragma unroll
            for (int r = 0; r < 8; r++) {
                float v = acc2[r] + hin[(n0 + r) * 64 + j];
                hout[(n0 + r) * 64 + j] = v;
                out[(size_t)(n0 + r) * 704 + col0 + j] = v;
            }
        }
        __syncthreads();  // protect hid before next chunk
    }
}

// ---------------- graph max pooling over node_emb cols 0..351 ----------------
__device__ __forceinline__ unsigned fmap(float v) {
    unsigned u = __float_as_uint(v);
    return (u & 0x80000000u) ? ~u : (u | 0x80000000u);
}

__global__ __launch_bounds__(384) void k_colmax(const float* __restrict__ out, unsigned* __restrict__ gmax) {
    int c = threadIdx.x;
    if (c >= 352) return;
    float m = -1e30f;
    for (int n = blockIdx.x; n < N_NODES; n += gridDim.x)
        m = fmaxf(m, out[(size_t)n * 704 + c]);
    atomicMax(gmax + c, fmap(m));
}

__global__ __launch_bounds__(384) void k_bcast(const unsigned* __restrict__ gmax, float* __restrict__ out) {
    int c = threadIdx.x;
    if (c >= 352) return;
    unsigned u = gmax[c];
    u = (u & 0x80000000u) ? (u ^ 0x80000000u) : ~u;
    float v = __uint_as_float(u);
    for (int n = blockIdx.x; n < N_NODES; n += gridDim.x)
        out[(size_t)n * 704 + 352 + c] = v;
}

// ---------------- host launcher ----------------
extern "C" void kernel_launch(void* const* d_in, const int* in_sizes, int n_in,
                              void* d_out, int out_size, void* d_ws, size_t ws_size,
                              hipStream_t stream)
{
    (void)in_sizes; (void)n_in; (void)out_size; (void)ws_size;
    const float* feat     = (const float*)d_in[0];
    const float* att_rc   = (const float*)d_in[1];
    const float* att_rp   = (const float*)d_in[2];
    const float* type_emb = (const float*)d_in[3];
    const float* rid_emb  = (const float*)d_in[4];
    const float* rc_W     = (const float*)d_in[5];
    const float* rc_b     = (const float*)d_in[6];
    const float* rp_W     = (const float*)d_in[7];
    const float* rp_b     = (const float*)d_in[8];
    const float* fe_W1    = (const float*)d_in[9];
    const float* fe_b1    = (const float*)d_in[10];
    const float* fe_W2    = (const float*)d_in[11];
    const float* fe_b2    = (const float*)d_in[12];
    const float* W_ni     = (const float*)d_in[13];
    const float* W_nj     = (const float*)d_in[14];
    const float* W_fij    = (const float*)d_in[15];
    const float* W_node   = (const float*)d_in[16];
    const float* b_node   = (const float*)d_in[17];
    const float* attn     = (const float*)d_in[18];
    const float* mlp_W1   = (const float*)d_in[19];
    const float* mlp_b1   = (const float*)d_in[20];
    const float* mlp_W2   = (const float*)d_in[21];
    const float* mlp_b2   = (const float*)d_in[22];
    const int* src   = (const int*)d_in[23];
    const int* dst   = (const int*)d_in[24];
    const int* etype = (const int*)d_in[25];
    const int* erid  = (const int*)d_in[26];
    float* out = (float*)d_out;

    // Workspace layout (byte cursor, all chunks 16B aligned).
    char* cur = (char*)d_ws;
    auto alloc = [&](size_t bytes) { char* p = cur; cur += (bytes + 15) & ~(size_t)15; return p; };
    float* h_a   = (float*)alloc((size_t)N_NODES * 64 * 4);
    float* h_b   = (float*)alloc((size_t)N_NODES * 64 * 4);
    bf16_t* s    = (bf16_t*)alloc((size_t)N_NODES * 384 * 2);
    float* ev    = (float*)alloc((size_t)N_EDGES * 2 * 4);
    float* agg   = (float*)alloc((size_t)N_NODES * 128 * 4);
    int* deg     = (int*)alloc((size_t)N_NODES * 4);
    int* rowptr  = (int*)alloc((size_t)(N_NODES + 1) * 4);
    int* cursor  = (int*)alloc((size_t)N_NODES * 4);
    int* eidx    = (int*)alloc((size_t)N_EDGES * 4);
    int* src_s   = (int*)alloc((size_t)N_EDGES * 4);
    int* dst_s   = (int*)alloc((size_t)N_EDGES * 4);
    int* etype_s = (int*)alloc((size_t)N_EDGES * 4);
    int* erid_s  = (int*)alloc((size_t)N_EDGES * 4);
    float* rc_s  = (float*)alloc((size_t)N_EDGES * 2 * 4);
    float* rp_s  = (float*)alloc((size_t)N_EDGES * 3 * 4);
    bf16_t* WT   = (bf16_t*)alloc((size_t)NLAYER * 128 * 64 * 2);
    int* bsum    = (int*)alloc(64 * 4);
    int* boff    = (int*)alloc(64 * 4);
    unsigned* gmax = (unsigned*)alloc(352 * 4);

    const int NB = (N_NODES + 1023) / 1024;  // 49

    k_zero32<<<(N_NODES + 255) / 256, 256, 0, stream>>>((unsigned*)deg, N_NODES);
    k_zero32<<<2, 256, 0, stream>>>(gmax, 352);
    k_hist<<<N_EDGES / 256, 256, 0, stream>>>(dst, deg);
    k_scan1<<<NB, 1024, 0, stream>>>(deg, rowptr, bsum);
    k_scan2<<<1, 64, 0, stream>>>(bsum, boff, NB);
    k_scan3<<<NB, 1024, 0, stream>>>(rowptr, boff);
    k_copy<<<(N_NODES + 255) / 256, 256, 0, stream>>>(rowptr, cursor);
    k_scatter<<<N_EDGES / 256, 256, 0, stream>>>(dst, cursor, eidx);
    k_sortgather<<<N_EDGES / 256, 256, 0, stream>>>(eidx, src, dst, etype, erid, att_rc, att_rp,
                                                    src_s, dst_s, etype_s, erid_s, rc_s, rp_s);
    k_wprep<<<128, 256, 0, stream>>>(W_fij, WT);
    k_fe<<<N_NODES / 4, 256, 0, stream>>>(feat, fe_W1, fe_b1, fe_W2, fe_b2, h_a, out);

    float* hc = h_a;
    float* hn = h_b;
    for (int l = 0; l < NLAYER; l++) {
        k_node3<<<dim3(768, 3), 128, 0, stream>>>(hc, W_ni + l * 64 * 128, W_nj + l * 64 * 128,
                                                  W_node + l * 64 * 128, b_node + l * 128, s);
        k_edge<<<2560, 256, 0, stream>>>(s, WT + l * 128 * 64, attn + l * 128,
                                         type_emb, rid_emb, rc_W, rc_b, rp_W, rp_b,
                                         rc_s, rp_s, etype_s, erid_s, src_s, dst_s, ev);
        k_soft_agg<<<4096, 256, 0, stream>>>(rowptr, src_s, ev, s, agg);
        k_mlp<<<1024, 128, 0, stream>>>(agg, mlp_W1 + l * 128 * 128, mlp_b1 + l * 128,
                                        mlp_W2 + l * 128 * 64, mlp_b2 + l * 64,
                                        hc, hn, out, 32 + 64 * (l + 1));
        float* tmp = hc; hc = hn; hn = tmp;
    }
    k_colmax<<<512, 384, 0, stream>>>(out, gmax);
    k_bcast<<<512, 384, 0, stream>>>(gmax, out);
}

// Round 5
// 1331.747 us; speedup vs baseline: 2.8352x; 1.3369x over previous
//
#include <hip/hip_runtime.h>
#include <math.h>

// Problem constants (fixed by the reference).
#define N_NODES 50000
#define N_EDGES 640000   // divisible by 32 (20000 tiles) and 256
#define NLAYER  4
#define NPAD    50016    // N_NODES rounded up to 32

typedef unsigned short bf16_t;
typedef __attribute__((ext_vector_type(8))) short s16x8;   // 8 bf16 = 4 VGPR (MFMA A/B frag)
typedef __attribute__((ext_vector_type(4))) float f32x4;   // MFMA C/D frag

__device__ __forceinline__ float gelu_f(float x) {
    return 0.5f * x * (1.0f + tanhf(0.7978845608028654f * (x + 0.044715f * x * x * x)));
}

__device__ __forceinline__ bf16_t f2bf(float f) {
    unsigned u = __float_as_uint(f);
    unsigned r = (u + 0x7FFFu + ((u >> 16) & 1u)) >> 16;   // RNE
    return (bf16_t)r;
}
__device__ __forceinline__ float bf2f(bf16_t h) { return __uint_as_float(((unsigned)h) << 16); }
__device__ __forceinline__ float bfl(unsigned x) { return __uint_as_float(x << 16); }
__device__ __forceinline__ float bfh(unsigned x) { return __uint_as_float(x & 0xFFFF0000u); }

// ---------------- CSR build (counting sort by dst) ----------------
__global__ void k_zero32(unsigned* p, int n) {
    int i = blockIdx.x * 256 + threadIdx.x;
    if (i < n) p[i] = 0u;
}

__global__ void k_hist(const int* __restrict__ dst, int* __restrict__ deg) {
    int i = blockIdx.x * 256 + threadIdx.x;
    if (i < N_EDGES) atomicAdd(&deg[dst[i]], 1);
}

__global__ void k_scan1(const int* __restrict__ deg, int* __restrict__ rowptr, int* __restrict__ bsum) {
    __shared__ int sd[1024];
    int gi = blockIdx.x * 1024 + threadIdx.x;
    int v = (gi < N_NODES) ? deg[gi] : 0;
    sd[threadIdx.x] = v;
    __syncthreads();
    for (int off = 1; off < 1024; off <<= 1) {
        int t2 = (threadIdx.x >= (unsigned)off) ? sd[threadIdx.x - off] : 0;
        __syncthreads();
        sd[threadIdx.x] += t2;
        __syncthreads();
    }
    if (gi < N_NODES) rowptr[gi] = sd[threadIdx.x] - v;  // block-local exclusive
    if (threadIdx.x == 1023) bsum[blockIdx.x] = sd[1023];
}

__global__ void k_scan2(const int* __restrict__ bsum, int* __restrict__ boff, int nb) {
    if (threadIdx.x == 0 && blockIdx.x == 0) {
        int run = 0;
        for (int b = 0; b < nb; b++) { boff[b] = run; run += bsum[b]; }
    }
}

__global__ void k_scan3(int* __restrict__ rowptr, const int* __restrict__ boff) {
    int gi = blockIdx.x * 1024 + threadIdx.x;
    if (gi < N_NODES) rowptr[gi] += boff[blockIdx.x];
    if (gi == 0) rowptr[N_NODES] = N_EDGES;
}

__global__ void k_copy(const int* __restrict__ a, int* __restrict__ b) {
    int i = blockIdx.x * 256 + threadIdx.x;
    if (i < N_NODES) b[i] = a[i];
}

__global__ void k_scatter(const int* __restrict__ dst, int* __restrict__ cursor, int* __restrict__ eidx) {
    int i = blockIdx.x * 256 + threadIdx.x;
    if (i < N_EDGES) {
        int p = atomicAdd(&cursor[dst[i]], 1);
        eidx[p] = i;
    }
}

// Gather all per-edge fields into dst-sorted order so downstream kernels are linear.
__global__ void k_sortgather(
    const int* __restrict__ eidx, const int* __restrict__ src, const int* __restrict__ dst,
    const int* __restrict__ etype, const int* __restrict__ erid,
    const float* __restrict__ att_rc, const float* __restrict__ att_rp,
    int* __restrict__ src_s, int* __restrict__ dst_s,
    int* __restrict__ etype_s, int* __restrict__ erid_s,
    float* __restrict__ rc_s, float* __restrict__ rp_s)
{
    int i = blockIdx.x * 256 + threadIdx.x;
    if (i < N_EDGES) {
        int e = eidx[i];
        src_s[i] = src[e];
        dst_s[i] = dst[e];
        etype_s[i] = etype[e];
        erid_s[i] = erid[e];
        rc_s[2 * i] = att_rc[2 * e];
        rc_s[2 * i + 1] = att_rc[2 * e + 1];
        rp_s[3 * i] = att_rp[3 * e];
        rp_s[3 * i + 1] = att_rp[3 * e + 1];
        rp_s[3 * i + 2] = att_rp[3 * e + 2];
    }
}

// All weight transposes to bf16, k-contiguous rows (MFMA A-operand friendly).
// WT   [L][128][64]  <- W_fij  [L][64][128]
// W3T  [L][384][64]  <- [W_ni|W_nj|W_node] [L][64][128] each
// W1T  [L][128][128] <- mlp_W1 [L][128][128]
// W2T  [L][64][128]  <- mlp_W2 [L][128][64]
__global__ void k_wprep(const float* __restrict__ Wfij, const float* __restrict__ Wni,
                        const float* __restrict__ Wnj, const float* __restrict__ Wnode,
                        const float* __restrict__ W1, const float* __restrict__ W2,
                        bf16_t* __restrict__ WT, bf16_t* __restrict__ W3T,
                        bf16_t* __restrict__ W1T, bf16_t* __restrict__ W2T)
{
    int idx = blockIdx.x * 256 + threadIdx.x;
    if (idx >= NLAYER * 57344) return;
    int l = idx / 57344, r = idx % 57344;
    if (r < 8192) {
        int n = r >> 6, k = r & 63;
        WT[l * 8192 + r] = f2bf(Wfij[l * 8192 + k * 128 + n]);
    } else if (r < 32768) {
        int q = r - 8192; int c = q >> 6, k = q & 63;
        const float* src = (c < 128) ? Wni : (c < 256) ? Wnj : Wnode;
        W3T[l * 24576 + q] = f2bf(src[l * 8192 + k * 128 + (c & 127)]);
    } else if (r < 49152) {
        int q = r - 32768; int n = q >> 7, k = q & 127;
        W1T[l * 16384 + q] = f2bf(W1[l * 16384 + k * 128 + n]);
    } else {
        int q = r - 49152; int j = q >> 7, k = q & 127;
        W2T[l * 8192 + q] = f2bf(W2[l * 8192 + k * 64 + j]);
    }
}

// ---------------- feature encoder: h0 = gelu(feat@W1+b1)@W2+b2 ----------------
__global__ __launch_bounds__(256) void k_fe(
    const float* __restrict__ feat, const float* __restrict__ W1, const float* __restrict__ b1,
    const float* __restrict__ W2, const float* __restrict__ b2,
    float* __restrict__ h, bf16_t* __restrict__ hb, float* __restrict__ out)
{
    __shared__ float hid[4][64];
    int w = threadIdx.x >> 6, lane = threadIdx.x & 63;
    int n = blockIdx.x * 4 + w;  // N divisible by 4
    float a = b1[lane];
#pragma unroll 8
    for (int k = 0; k < 32; k++) a = fmaf(feat[n * 32 + k], W1[k * 64 + lane], a);
    hid[w][lane] = gelu_f(a);
    __syncthreads();
    float o = b2[lane];
#pragma unroll 8
    for (int k = 0; k < 64; k++) o = fmaf(hid[w][k], W2[k * 64 + lane], o);
    h[n * 64 + lane] = o;
    hb[n * 64 + lane] = f2bf(o);
    out[n * 704 + 32 + lane] = o;
    if (lane < 32) out[n * 704 + lane] = feat[n * 32 + lane];
}

// ---------------- s = h @ [W_ni | W_nj | W_node(+b)] -> [NPAD,384] bf16, MFMA ----------------
// A = W3T (out-col c as D-row), B = hb (node as D-col). Per block: 32 nodes x 384 cols.
// Wave: ng = node-tile (w&1), ch = 192-col half (w>>1). Lane holds node = ng*16+l16,
// 4 consecutive c per tile -> ushort4 stores.
__global__ __launch_bounds__(256) void k_node3(
    const bf16_t* __restrict__ hb, const bf16_t* __restrict__ W3T,
    const float* __restrict__ bnode, bf16_t* __restrict__ s)
{
    __shared__ __align__(16) bf16_t hbS[32 * 72];
    const int t = threadIdx.x;
    const int wave = t >> 6, lane = t & 63, l16 = lane & 15, quad = lane >> 4;
    const int n0 = blockIdx.x * 32;
    {   // stage hb tile: 32 rows x 128B
        int r = t >> 3, sg = t & 7;
        *(s16x8*)(hbS + r * 72 + sg * 8) = *(const s16x8*)(hb + (size_t)(n0 + r) * 64 + sg * 8);
    }
    __syncthreads();
    const int ng = wave & 1, ch = wave >> 1;
    const s16x8 B0 = *(const s16x8*)(hbS + (ng * 16 + l16) * 72 + quad * 8);
    const s16x8 B1 = *(const s16x8*)(hbS + (ng * 16 + l16) * 72 + 32 + quad * 8);
    const int node = n0 + ng * 16 + l16;
#pragma unroll
    for (int nt = 0; nt < 12; nt++) {
        int c0 = ch * 192 + nt * 16;
        const s16x8 A0 = *(const s16x8*)(W3T + (size_t)(c0 + l16) * 64 + quad * 8);
        const s16x8 A1 = *(const s16x8*)(W3T + (size_t)(c0 + l16) * 64 + 32 + quad * 8);
        f32x4 acc = {0.f, 0.f, 0.f, 0.f};
        acc = __builtin_amdgcn_mfma_f32_16x16x32_bf16(A0, B0, acc, 0, 0, 0);
        acc = __builtin_amdgcn_mfma_f32_16x16x32_bf16(A1, B1, acc, 0, 0, 0);
        int cb = c0 + quad * 4;
        float4 bv = make_float4(0.f, 0.f, 0.f, 0.f);
        if (cb >= 256) bv = *(const float4*)(bnode + cb - 256);
        ushort4 o;
        o.x = f2bf(acc[0] + bv.x);
        o.y = f2bf(acc[1] + bv.y);
        o.z = f2bf(acc[2] + bv.z);
        o.w = f2bf(acc[3] + bv.w);
        *(ushort4*)(s + (size_t)node * 384 + cb) = o;
    }
}

// ---------------- fused edge kernel, MFMA version (unchanged from R4) ----------------
__global__ __launch_bounds__(256) void k_edge(
    const bf16_t* __restrict__ s, const bf16_t* __restrict__ WT,
    const float* __restrict__ attn,
    const float* __restrict__ type_emb, const float* __restrict__ rid_emb,
    const float* __restrict__ rcW, const float* __restrict__ rcb,
    const float* __restrict__ rpW, const float* __restrict__ rpb,
    const float* __restrict__ rc_s, const float* __restrict__ rp_s,
    const int* __restrict__ etype_s, const int* __restrict__ erid_s,
    const int* __restrict__ src_s, const int* __restrict__ dst_s,
    float* __restrict__ evals)
{
    __shared__ __align__(16) bf16_t efA[32 * 72];
    __shared__ __align__(16) bf16_t SND[32 * 136];
    const int t = threadIdx.x;
    const int wave = t >> 6, lane = t & 63;
    const int l16 = lane & 15, quad = lane >> 4;
    const int eg = wave & 1, head = wave >> 1;

    s16x8 Aw[4][2];
    float4 att4[4];
#pragma unroll
    for (int mt = 0; mt < 4; mt++) {
        const bf16_t* wrow = WT + (head * 64 + mt * 16 + l16) * 64 + quad * 8;
        Aw[mt][0] = *(const s16x8*)(wrow);
        Aw[mt][1] = *(const s16x8*)(wrow + 32);
        att4[mt] = *(const float4*)(attn + head * 64 + mt * 16 + quad * 4);
    }

    for (int tile = blockIdx.x; tile < N_EDGES / 32; tile += gridDim.x) {
        const int eb = tile * 32;
        __syncthreads();
        {   // Phase A: edge embedding -> efA
            int e = t & 31, kg = (t >> 5) * 8;
            int i = eb + e;
            int et = etype_s[i] * 64, er = erid_s[i] * 64;
            float rc0 = rc_s[i * 2 + 0], rc1 = rc_s[i * 2 + 1];
            float rp0 = rp_s[i * 3 + 0], rp1 = rp_s[i * 3 + 1], rp2 = rp_s[i * 3 + 2];
            bf16_t tmp[8];
#pragma unroll
            for (int kk = 0; kk < 8; kk++) {
                int k = kg + kk;
                float v = type_emb[et + k] + rid_emb[er + k] + rcb[k] + rpb[k];
                v = fmaf(rc0, rcW[k], v);
                v = fmaf(rc1, rcW[64 + k], v);
                v = fmaf(rp0, rpW[k], v);
                v = fmaf(rp1, rpW[64 + k], v);
                v = fmaf(rp2, rpW[128 + k], v);
                tmp[kk] = f2bf(v);
            }
            *(s16x8*)(&efA[e * 72 + kg]) = *(const s16x8*)tmp;
        }
        {   // Phase A2: SND = s_ni[src] + s_nj[dst]
#pragma unroll
            for (int j = 0; j < 2; j++) {
                int c = t * 2 + j;
                int e = c >> 4, p = c & 15;
                int i = eb + e;
                const uint4 U = *(const uint4*)(s + (size_t)src_s[i] * 384 + p * 8);
                const uint4 V = *(const uint4*)(s + (size_t)dst_s[i] * 384 + 128 + p * 8);
                bf16_t o[8];
                o[0] = f2bf(bfl(U.x) + bfl(V.x)); o[1] = f2bf(bfh(U.x) + bfh(V.x));
                o[2] = f2bf(bfl(U.y) + bfl(V.y)); o[3] = f2bf(bfh(U.y) + bfh(V.y));
                o[4] = f2bf(bfl(U.z) + bfl(V.z)); o[5] = f2bf(bfh(U.z) + bfh(V.z));
                o[6] = f2bf(bfl(U.w) + bfl(V.w)); o[7] = f2bf(bfh(U.w) + bfh(V.w));
                *(s16x8*)(&SND[e * 136 + p * 8]) = *(const s16x8*)o;
            }
        }
        __syncthreads();

        const int e = eg * 16 + l16;
        const s16x8 B0 = *(const s16x8*)(&efA[e * 72 + quad * 8]);
        const s16x8 B1 = *(const s16x8*)(&efA[e * 72 + 32 + quad * 8]);
        f32x4 acc[4];
#pragma unroll
        for (int mt = 0; mt < 4; mt++) {
            f32x4 a = {0.f, 0.f, 0.f, 0.f};
            a = __builtin_amdgcn_mfma_f32_16x16x32_bf16(Aw[mt][0], B0, a, 0, 0, 0);
            a = __builtin_amdgcn_mfma_f32_16x16x32_bf16(Aw[mt][1], B1, a, 0, 0, 0);
            acc[mt] = a;
        }

        float p = 0.f;
#pragma unroll
        for (int mt = 0; mt < 4; mt++) {
            const ushort4 sv = *(const ushort4*)(&SND[e * 136 + mt * 16 + quad * 4]);
            float f0 = acc[mt][0] + bf2f(sv.x);
            float f1 = acc[mt][1] + bf2f(sv.y);
            float f2 = acc[mt][2] + bf2f(sv.z);
            float f3 = acc[mt][3] + bf2f(sv.w);
            f0 = (f0 >= 0.f) ? f0 : 0.2f * f0;
            f1 = (f1 >= 0.f) ? f1 : 0.2f * f1;
            f2 = (f2 >= 0.f) ? f2 : 0.2f * f2;
            f3 = (f3 >= 0.f) ? f3 : 0.2f * f3;
            p = fmaf(f0, att4[mt].x, p);
            p = fmaf(f1, att4[mt].y, p);
            p = fmaf(f2, att4[mt].z, p);
            p = fmaf(f3, att4[mt].w, p);
        }
        p += __shfl_xor(p, 16);
        p += __shfl_xor(p, 32);
        if (quad == 0) evals[(eb + e) * 2 + head] = p;
    }
}

// ---------------- per-dst softmax + aggregation -> aggb bf16 ----------------
__global__ __launch_bounds__(256) void k_soft_agg(
    const int* __restrict__ rowptr, const int* __restrict__ src_s,
    const float* __restrict__ evals, const bf16_t* __restrict__ s,
    unsigned* __restrict__ aggb)   // [NPAD][64] uints = [NPAD][128] bf16
{
    int lane = threadIdx.x & 63;
    int wid = (blockIdx.x * 256 + threadIdx.x) >> 6;
    int nw = (gridDim.x * 256) >> 6;
    const int h1 = (lane >= 32) ? 1 : 0;
    const int half = lane & 31;
    for (int n = wid; n < N_NODES; n += nw) {
        int r0 = rowptr[n], r1 = rowptr[n + 1];
        unsigned* aout = aggb + (size_t)n * 64 + lane;
        if (r0 == r1) { *aout = 0u; continue; }
        float mm = -1e30f;
        for (int i = r0 + half; i < r1; i += 32) mm = fmaxf(mm, evals[2 * i + h1]);
#pragma unroll
        for (int off = 1; off < 32; off <<= 1) mm = fmaxf(mm, __shfl_xor(mm, off));
        float z = 0.f;
        for (int i = r0 + half; i < r1; i += 32) z += expf(evals[2 * i + h1] - mm);
#pragma unroll
        for (int off = 1; off < 32; off <<= 1) z += __shfl_xor(z, off);
        float rz = 1.f / z;
        float acc0 = 0.f, acc1 = 0.f;
        for (int i = r0; i < r1; i += 8) {
            int cnt = r1 - i;
            unsigned cc[8]; float ww[8];
#pragma unroll
            for (int j = 0; j < 8; j++) {
                if (j < cnt) {
                    cc[j] = *(const unsigned*)(s + (size_t)src_s[i + j] * 384 + 256 + 2 * lane);
                    ww[j] = expf(evals[2 * (i + j) + h1] - mm) * rz;
                } else { cc[j] = 0u; ww[j] = 0.f; }
            }
#pragma unroll
            for (int j = 0; j < 8; j++) {
                acc0 = fmaf(ww[j], bfl(cc[j]), acc0);
                acc1 = fmaf(ww[j], bfh(cc[j]), acc1);
            }
        }
        *aout = (unsigned)f2bf(acc0) | ((unsigned)f2bf(acc1) << 16);
    }
}

// ---------------- node MLP + residual, MFMA: h' = gelu(agg@W1+b1)@W2+b2 + h ----------------
// GEMM1: A=W1T (hid-feature rows), B=agg (node cols) -> hid in LDS (node-major).
// GEMM2: A=W2T (out-feature rows), B=hid -> lane holds 4 consecutive j of one node.
__global__ __launch_bounds__(256) void k_mlp(
    const bf16_t* __restrict__ aggb, const bf16_t* __restrict__ W1T, const float* __restrict__ b1,
    const bf16_t* __restrict__ W2T, const float* __restrict__ b2,
    const float* __restrict__ hin, float* __restrict__ hout, bf16_t* __restrict__ houtb,
    float* __restrict__ out, int col0)
{
    __shared__ __align__(16) bf16_t aggS[32 * 136];
    __shared__ __align__(16) bf16_t hidS[32 * 136];
    const int t = threadIdx.x;
    const int wave = t >> 6, lane = t & 63, l16 = lane & 15, quad = lane >> 4;
    const int n0 = blockIdx.x * 32;
    {   // stage agg tile: 32 rows x 256B (32B per thread)
        int r = t >> 3, sg = t & 7;
        *(s16x8*)(aggS + r * 136 + sg * 16) =
            *(const s16x8*)(aggb + (size_t)(n0 + r) * 128 + sg * 16);
        *(s16x8*)(aggS + r * 136 + sg * 16 + 8) =
            *(const s16x8*)(aggb + (size_t)(n0 + r) * 128 + sg * 16 + 8);
    }
    __syncthreads();
    const int ng = wave & 1, nh = wave >> 1;
    const int node = n0 + ng * 16 + l16;
    {   // GEMM1 + gelu -> hidS
        const bf16_t* brow = aggS + (ng * 16 + l16) * 136 + quad * 8;
        s16x8 B[4];
#pragma unroll
        for (int ks = 0; ks < 4; ks++) B[ks] = *(const s16x8*)(brow + ks * 32);
#pragma unroll
        for (int nt = 0; nt < 4; nt++) {
            int nb = nh * 64 + nt * 16;
            f32x4 acc = {0.f, 0.f, 0.f, 0.f};
#pragma unroll
            for (int ks = 0; ks < 4; ks++) {
                const s16x8 A = *(const s16x8*)(W1T + (size_t)(nb + l16) * 128 + ks * 32 + quad * 8);
                acc = __builtin_amdgcn_mfma_f32_16x16x32_bf16(A, B[ks], acc, 0, 0, 0);
            }
            const float4 bv = *(const float4*)(b1 + nb + quad * 4);
            ushort4 o;
            o.x = f2bf(gelu_f(acc[0] + bv.x));
            o.y = f2bf(gelu_f(acc[1] + bv.y));
            o.z = f2bf(gelu_f(acc[2] + bv.z));
            o.w = f2bf(gelu_f(acc[3] + bv.w));
            *(ushort4*)(hidS + (ng * 16 + l16) * 136 + nb + quad * 4) = o;
        }
    }
    __syncthreads();
    {   // GEMM2 + bias + residual -> hout/houtb/out
        const int jh = wave >> 1;
        const bf16_t* hrow = hidS + (ng * 16 + l16) * 136 + quad * 8;
        s16x8 H[4];
#pragma unroll
        for (int ks = 0; ks < 4; ks++) H[ks] = *(const s16x8*)(hrow + ks * 32);
#pragma unroll
        for (int jt = 0; jt < 2; jt++) {
            int jb = jh * 32 + jt * 16;
            f32x4 acc = {0.f, 0.f, 0.f, 0.f};
#pragma unroll
            for (int ks = 0; ks < 4; ks++) {
                const s16x8 A = *(const s16x8*)(W2T + (size_t)(jb + l16) * 128 + ks * 32 + quad * 8);
                acc = __builtin_amdgcn_mfma_f32_16x16x32_bf16(A, H[ks], acc, 0, 0, 0);
            }
            int j0 = jb + quad * 4;
            const float4 bv = *(const float4*)(b2 + j0);
            const float4 hv = *(const float4*)(hin + (size_t)node * 64 + j0);
            float4 v;
            v.x = acc[0] + bv.x + hv.x;
            v.y = acc[1] + bv.y + hv.y;
            v.z = acc[2] + bv.z + hv.z;
            v.w = acc[3] + bv.w + hv.w;
            *(float4*)(hout + (size_t)node * 64 + j0) = v;
            ushort4 ob;
            ob.x = f2bf(v.x); ob.y = f2bf(v.y); ob.z = f2bf(v.z); ob.w = f2bf(v.w);
            *(ushort4*)(houtb + (size_t)node * 64 + j0) = ob;
            if (node < N_NODES)
                *(float4*)(out + (size_t)node * 704 + col0 + j0) = v;
        }
    }
}

// ---------------- graph max pooling over node_emb cols 0..351 ----------------
__device__ __forceinline__ unsigned fmap(float v) {
    unsigned u = __float_as_uint(v);
    return (u & 0x80000000u) ? ~u : (u | 0x80000000u);
}

__global__ __launch_bounds__(384) void k_colmax(const float* __restrict__ out, unsigned* __restrict__ gmax) {
    int c = threadIdx.x;
    if (c >= 352) return;
    float m = -1e30f;
    for (int n = blockIdx.x; n < N_NODES; n += gridDim.x)
        m = fmaxf(m, out[(size_t)n * 704 + c]);
    atomicMax(gmax + c, fmap(m));
}

__global__ __launch_bounds__(384) void k_bcast(const unsigned* __restrict__ gmax, float* __restrict__ out) {
    int c = threadIdx.x;
    if (c >= 352) return;
    unsigned u = gmax[c];
    u = (u & 0x80000000u) ? (u ^ 0x80000000u) : ~u;
    float v = __uint_as_float(u);
    for (int n = blockIdx.x; n < N_NODES; n += gridDim.x)
        out[(size_t)n * 704 + 352 + c] = v;
}

// ---------------- host launcher ----------------
extern "C" void kernel_launch(void* const* d_in, const int* in_sizes, int n_in,
                              void* d_out, int out_size, void* d_ws, size_t ws_size,
                              hipStream_t stream)
{
    (void)in_sizes; (void)n_in; (void)out_size; (void)ws_size;
    const float* feat     = (const float*)d_in[0];
    const float* att_rc   = (const float*)d_in[1];
    const float* att_rp   = (const float*)d_in[2];
    const float* type_emb = (const float*)d_in[3];
    const float* rid_emb  = (const float*)d_in[4];
    const float* rc_W     = (const float*)d_in[5];
    const float* rc_b     = (const float*)d_in[6];
    const float* rp_W     = (const float*)d_in[7];
    const float* rp_b     = (const float*)d_in[8];
    const float* fe_W1    = (const float*)d_in[9];
    const float* fe_b1    = (const float*)d_in[10];
    const float* fe_W2    = (const float*)d_in[11];
    const float* fe_b2    = (const float*)d_in[12];
    const float* W_ni     = (const float*)d_in[13];
    const float* W_nj     = (const float*)d_in[14];
    const float* W_fij    = (const float*)d_in[15];
    const float* W_node   = (const float*)d_in[16];
    const float* b_node   = (const float*)d_in[17];
    const float* attn     = (const float*)d_in[18];
    const float* mlp_W1   = (const float*)d_in[19];
    const float* mlp_b1   = (const float*)d_in[20];
    const float* mlp_W2   = (const float*)d_in[21];
    const float* mlp_b2   = (const float*)d_in[22];
    const int* src   = (const int*)d_in[23];
    const int* dst   = (const int*)d_in[24];
    const int* etype = (const int*)d_in[25];
    const int* erid  = (const int*)d_in[26];
    float* out = (float*)d_out;

    // Workspace layout (byte cursor, all chunks 16B aligned).
    char* cur = (char*)d_ws;
    auto alloc = [&](size_t bytes) { char* p = cur; cur += (bytes + 15) & ~(size_t)15; return p; };
    float* h_a    = (float*)alloc((size_t)NPAD * 64 * 4);
    float* h_b    = (float*)alloc((size_t)NPAD * 64 * 4);
    bf16_t* hb_a  = (bf16_t*)alloc((size_t)NPAD * 64 * 2);
    bf16_t* hb_b  = (bf16_t*)alloc((size_t)NPAD * 64 * 2);
    bf16_t* s     = (bf16_t*)alloc((size_t)NPAD * 384 * 2);
    float* ev     = (float*)alloc((size_t)N_EDGES * 2 * 4);
    bf16_t* aggb  = (bf16_t*)alloc((size_t)NPAD * 128 * 2);
    int* deg     = (int*)alloc((size_t)N_NODES * 4);
    int* rowptr  = (int*)alloc((size_t)(N_NODES + 1) * 4);
    int* cursor  = (int*)alloc((size_t)N_NODES * 4);
    int* eidx    = (int*)alloc((size_t)N_EDGES * 4);
    int* src_s   = (int*)alloc((size_t)N_EDGES * 4);
    int* dst_s   = (int*)alloc((size_t)N_EDGES * 4);
    int* etype_s = (int*)alloc((size_t)N_EDGES * 4);
    int* erid_s  = (int*)alloc((size_t)N_EDGES * 4);
    float* rc_s  = (float*)alloc((size_t)N_EDGES * 2 * 4);
    float* rp_s  = (float*)alloc((size_t)N_EDGES * 3 * 4);
    bf16_t* WT   = (bf16_t*)alloc((size_t)NLAYER * 128 * 64 * 2);
    bf16_t* W3T  = (bf16_t*)alloc((size_t)NLAYER * 384 * 64 * 2);
    bf16_t* W1T  = (bf16_t*)alloc((size_t)NLAYER * 128 * 128 * 2);
    bf16_t* W2T  = (bf16_t*)alloc((size_t)NLAYER * 64 * 128 * 2);
    int* bsum    = (int*)alloc(64 * 4);
    int* boff    = (int*)alloc(64 * 4);
    unsigned* gmax = (unsigned*)alloc(352 * 4);

    const int NB = (N_NODES + 1023) / 1024;  // 49

    k_zero32<<<(N_NODES + 255) / 256, 256, 0, stream>>>((unsigned*)deg, N_NODES);
    k_zero32<<<2, 256, 0, stream>>>(gmax, 352);
    k_hist<<<N_EDGES / 256, 256, 0, stream>>>(dst, deg);
    k_scan1<<<NB, 1024, 0, stream>>>(deg, rowptr, bsum);
    k_scan2<<<1, 64, 0, stream>>>(bsum, boff, NB);
    k_scan3<<<NB, 1024, 0, stream>>>(rowptr, boff);
    k_copy<<<(N_NODES + 255) / 256, 256, 0, stream>>>(rowptr, cursor);
    k_scatter<<<N_EDGES / 256, 256, 0, stream>>>(dst, cursor, eidx);
    k_sortgather<<<N_EDGES / 256, 256, 0, stream>>>(eidx, src, dst, etype, erid, att_rc, att_rp,
                                                    src_s, dst_s, etype_s, erid_s, rc_s, rp_s);
    k_wprep<<<(NLAYER * 57344 + 255) / 256, 256, 0, stream>>>(
        W_fij, W_ni, W_nj, W_node, mlp_W1, mlp_W2, WT, W3T, W1T, W2T);
    k_fe<<<N_NODES / 4, 256, 0, stream>>>(feat, fe_W1, fe_b1, fe_W2, fe_b2, h_a, hb_a, out);

    float* hc = h_a;  bf16_t* hbc = hb_a;
    float* hn = h_b;  bf16_t* hbn = hb_b;
    for (int l = 0; l < NLAYER; l++) {
        k_node3<<<NPAD / 32, 256, 0, stream>>>(hbc, W3T + (size_t)l * 384 * 64, b_node + l * 128, s);
        k_edge<<<2560, 256, 0, stream>>>(s, WT + l * 128 * 64, attn + l * 128,
                                         type_emb, rid_emb, rc_W, rc_b, rp_W, rp_b,
                                         rc_s, rp_s, etype_s, erid_s, src_s, dst_s, ev);
        k_soft_agg<<<4096, 256, 0, stream>>>(rowptr, src_s, ev, s, (unsigned*)aggb);
        k_mlp<<<NPAD / 32, 256, 0, stream>>>(aggb, W1T + (size_t)l * 128 * 128, mlp_b1 + l * 128,
                                             W2T + (size_t)l * 64 * 128, mlp_b2 + l * 64,
                                             hc, hn, hbn, out, 32 + 64 * (l + 1));
        float* tf = hc; hc = hn; hn = tf;
        bf16_t* tb = hbc; hbc = hbn; hbn = tb;
    }
    k_colmax<<<512, 384, 0, stream>>>(out, gmax);
    k_bcast<<<512, 384, 0, stream>>>(gmax, out);
}